// Round 7
// baseline (376.340 us; speedup 1.0000x reference)
//
#include <hip/hip_runtime.h>
#include <cstdint>
#include <cstddef>

typedef float f32x4 __attribute__((ext_vector_type(4)));
typedef __bf16 bf16x8 __attribute__((ext_vector_type(8)));

#define BB 16
#define SEQ 1024
#define DMODEL 768
#define NHEAD 12
#define HDIM 64
#define MTOT (BB * SEQ)
#define NQKV (3 * DMODEL)
// 0.125 (hd^-0.5) * log2(e): QK^T then exp2 == exp(0.125 * qk)
#define QSCALE 0.18033688011112042f

static __device__ __forceinline__ unsigned short f2bf(float f) {
  unsigned int u = __builtin_bit_cast(unsigned int, f);
  u += 0x7fffu + ((u >> 16) & 1u);
  return (unsigned short)(u >> 16);
}

static __device__ __forceinline__ unsigned cvt_pk_bf16(float lo, float hi) {
  unsigned r;
  asm("v_cvt_pk_bf16_f32 %0, %1, %2" : "=v"(r) : "v"(lo), "v"(hi));
  return r;
}

static __device__ __forceinline__ void gload_lds16(const void* g, void* l) {
  __builtin_amdgcn_global_load_lds((__attribute__((address_space(1))) void*)g,
                                   (__attribute__((address_space(3))) void*)l,
                                   16, 0, 0);
}

// ---- prep: f32 -> bf16 convert (vectorized) ----
__global__ void k_cvt_bf16(const float4* __restrict__ in, ushort4* __restrict__ out, int n4) {
  int stride = gridDim.x * blockDim.x;
  for (int i = blockIdx.x * blockDim.x + threadIdx.x; i < n4; i += stride) {
    float4 v = in[i];
    ushort4 o;
    o.x = f2bf(v.x); o.y = f2bf(v.y); o.z = f2bf(v.z); o.w = f2bf(v.w);
    out[i] = o;
  }
}

// ---- prep: transpose f32 [R][C] -> bf16 [C][R] ----
__global__ void k_transpose_bf16(const float* __restrict__ in, unsigned short* __restrict__ out,
                                 int R, int C) {
  __shared__ float tile[32][33];
  int tx = threadIdx.x & 31, ty = threadIdx.x >> 5;
  int c0 = blockIdx.x * 32, r0 = blockIdx.y * 32;
#pragma unroll
  for (int i = 0; i < 4; ++i)
    tile[ty + i * 8][tx] = in[(size_t)(r0 + ty + i * 8) * C + c0 + tx];
  __syncthreads();
#pragma unroll
  for (int i = 0; i < 4; ++i)
    out[(size_t)(c0 + ty + i * 8) * R + r0 + tx] = f2bf(tile[tx][ty + i * 8]);
}

// ---- GEMM C[M,N] = A[M,K] * Bt[N,K]^T, bf16 in, f32 accum ----
// 128(m) x 256(n) tile, BK=32, DOUBLE-buffered (48 KB -> 3 blocks/CU), 4 waves
// each computing 64x128 (acc 4x8). ONE __syncthreads per K-tile: barrier drains
// the loads for tile t (issued one full compute-phase earlier), then tile t+1's
// global_load_lds are issued into the freed buffer BEFORE compute(t) -> load
// latency overlaps MFMA (T14 issue-early). Occupancy/TLP over deep pipelining.
// Swizzle (rule 21): linear LDS dest, source 16B-block ^= (row>>1)&3, read elem
// offset ^= ((row>>1)&3)*8 -> 2-way bank aliasing (free).
// MODE 0: outF = C + bias (f32). MODE 1: scatter to Q (pre-scaled), K, V^T.
template <int MODE>
__global__ __launch_bounds__(256) void k_gemm_bt(
    const unsigned short* __restrict__ A, const unsigned short* __restrict__ Bt,
    int M, int N, int K, int nwg,
    float* __restrict__ outF, const float* __restrict__ bias,
    unsigned short* __restrict__ Qd, unsigned short* __restrict__ Kd,
    unsigned short* __restrict__ Vt) {
  __shared__ __align__(16) unsigned short As[2][128 * 32];  // 16 KB
  __shared__ __align__(16) unsigned short Bs[2][256 * 32];  // 32 KB
  const int tid = threadIdx.x;
  const int lane = tid & 63, wid = tid >> 6;
  const int ln15 = lane & 15, lh = lane >> 4;
  const int wr = wid >> 1, wc = wid & 1;
  // XCD-aware flat-grid swizzle (nwg % 8 == 0): each XCD gets a contiguous chunk
  const int o = blockIdx.x;
  const int sid = (o & 7) * (nwg >> 3) + (o >> 3);
  const int m0 = (sid & 127) * 128;       // m-fastest: consecutive sid share B n-panel
  const int n0 = (sid >> 7) * 256;
  f32x4 acc[4][8] = {};
  // staging: chunk = 1KB = 16 rows x 64B; lane -> row (lane>>2), phys blk (lane&3);
  // source carries the inverse swizzle: src_blk = (lane&3) ^ ((lane>>3)&3)
  const int srow = lane >> 2;
  const int sblk = ((lane & 3) ^ ((lane >> 3) & 3)) * 8;
  // fragment-read swizzle: phys elem = (lh*8) ^ fswz, fswz = ((row>>1)&3)*8
  const int fswz = ((ln15 >> 1) & 3) << 3;
  const int nt = K >> 5;

  auto stage = [&](int kt, int s) {
    const int k0 = kt * 32;
#pragma unroll
    for (int c = 0; c < 2; ++c) {  // A: 8 chunks, wave takes 2
      const int ch = wid * 2 + c;
      gload_lds16(A + (size_t)(m0 + ch * 16 + srow) * K + k0 + sblk, &As[s][ch * 512]);
    }
#pragma unroll
    for (int c = 0; c < 4; ++c) {  // B: 16 chunks, wave takes 4
      const int ch = wid * 4 + c;
      gload_lds16(Bt + (size_t)(n0 + ch * 16 + srow) * K + k0 + sblk, &Bs[s][ch * 512]);
    }
  };

  stage(0, 0);
  for (int kt = 0; kt < nt; ++kt) {
    const int s = kt & 1;
    __syncthreads();                       // drains stage(kt); frees buf s^1
    if (kt + 1 < nt) stage(kt + 1, s ^ 1); // issue-early: overlaps compute below
    bf16x8 af[4], bfv[8];
#pragma unroll
    for (int mt = 0; mt < 4; ++mt)
      af[mt] = *reinterpret_cast<const bf16x8*>(
          &As[s][(wr * 64 + mt * 16 + ln15) * 32 + ((lh * 8) ^ fswz)]);
#pragma unroll
    for (int nn = 0; nn < 8; ++nn)
      bfv[nn] = *reinterpret_cast<const bf16x8*>(
          &Bs[s][(wc * 128 + nn * 16 + ln15) * 32 + ((lh * 8) ^ fswz)]);
#pragma unroll
    for (int mt = 0; mt < 4; ++mt)
#pragma unroll
      for (int nn = 0; nn < 8; ++nn)
        acc[mt][nn] = __builtin_amdgcn_mfma_f32_16x16x32_bf16(af[mt], bfv[nn], acc[mt][nn], 0, 0, 0);
  }

#pragma unroll
  for (int mt = 0; mt < 4; ++mt) {
#pragma unroll
    for (int nn = 0; nn < 8; ++nn) {
#pragma unroll
      for (int r = 0; r < 4; ++r) {
        const int m = m0 + wr * 64 + mt * 16 + lh * 4 + r;
        const int n = n0 + wc * 128 + nn * 16 + ln15;
        const float v = acc[mt][nn][r];
        if (MODE == 0) {
          outF[(size_t)m * N + n] = v + bias[n];
        } else {
          const int which = n / DMODEL;
          const int rr = n - which * DMODEL;
          const int h = rr >> 6, d = rr & 63;
          const int b = m >> 10, nr = m & 1023;
          const size_t bh = (size_t)(b * NHEAD + h);
          if (which == 0)      Qd[(bh * SEQ + nr) * HDIM + d] = f2bf(v * QSCALE);
          else if (which == 1) Kd[(bh * SEQ + nr) * HDIM + d] = f2bf(v);
          else                 Vt[(bh * HDIM + d) * SEQ + nr] = f2bf(v);
        }
      }
    }
  }
}

// ---- fused flash attention, swapped-QK^T in-register softmax ----
// K/V double-buffered; ONE __syncthreads per KV-tile with issue-early staging
// (same T14 transform as the GEMM): barrier drains stage(kb), stage(kb+1) is
// issued into the freed buffer before compute(kb).
__global__ __launch_bounds__(256) void k_attn(
    const unsigned short* __restrict__ Qd, const unsigned short* __restrict__ Kd,
    const unsigned short* __restrict__ Vt, unsigned short* __restrict__ O) {
  __shared__ __align__(16) unsigned short Ks[2][64 * 64];   // [kpos][d], swizzled
  __shared__ __align__(16) unsigned short Vs[2][64 * 64];   // [d][kpos], swizzled
  __shared__ __align__(16) unsigned short Ps[4][16 * 72];   // per-wave P [q][kpos]
  const int tid = threadIdx.x;
  const int lane = tid & 63, w = tid >> 6;
  const int ln15 = lane & 15, lh = lane >> 4;
  const int bid = blockIdx.x;
  const int qb = bid & 15;
  const int h = (bid >> 4) % NHEAD;
  const int b = bid / (16 * NHEAD);
  const size_t bh = (size_t)(b * NHEAD + h);
  const unsigned short* Qbase = Qd + (bh * SEQ + (size_t)qb * 64 + w * 16) * HDIM;
  const unsigned short* Kbase = Kd + bh * SEQ * HDIM;
  const unsigned short* Vbase = Vt + bh * HDIM * SEQ;

  const int srow = lane >> 3;
  const int sblk = ((lane & 7) ^ srow) * 8;
  const int swz = (ln15 & 7) << 3;

  auto stage = [&](int kb, int s) {
#pragma unroll
    for (int c2 = 0; c2 < 2; ++c2) {
      const int c = w * 2 + c2;
      const int row = c * 8 + srow;
      gload_lds16(Kbase + (size_t)(kb * 64 + row) * 64 + sblk, &Ks[s][c * 512]);
      gload_lds16(Vbase + (size_t)row * SEQ + kb * 64 + sblk, &Vs[s][c * 512]);
    }
  };

  bf16x8 aq[2];
#pragma unroll
  for (int ch = 0; ch < 2; ++ch)
    aq[ch] = *reinterpret_cast<const bf16x8*>(Qbase + (size_t)ln15 * HDIM + ch * 32 + lh * 8);

  f32x4 acc[4] = {};
  float mr = -1e30f, lr = 0.f;

  stage(0, 0);
  for (int kb = 0; kb < SEQ / 64; ++kb) {
    const int s = kb & 1;
    __syncthreads();                           // drains stage(kb); frees buf s^1
    if (kb + 1 < SEQ / 64) stage(kb + 1, s ^ 1);

    f32x4 sv[4] = {};
    __builtin_amdgcn_s_setprio(1);
#pragma unroll
    for (int t = 0; t < 4; ++t) {
#pragma unroll
      for (int ch = 0; ch < 2; ++ch) {
        bf16x8 bk = *reinterpret_cast<const bf16x8*>(
            &Ks[s][(t * 16 + ln15) * 64 + ((ch * 32 + lh * 8) ^ swz)]);
        sv[t] = __builtin_amdgcn_mfma_f32_16x16x32_bf16(bk, aq[ch], sv[t], 0, 0, 0);
      }
    }
    __builtin_amdgcn_s_setprio(0);

    float bm;
    {
      const float a0 = fmaxf(fmaxf(sv[0][0], sv[0][1]), fmaxf(sv[0][2], sv[0][3]));
      const float a1 = fmaxf(fmaxf(sv[1][0], sv[1][1]), fmaxf(sv[1][2], sv[1][3]));
      const float a2 = fmaxf(fmaxf(sv[2][0], sv[2][1]), fmaxf(sv[2][2], sv[2][3]));
      const float a3 = fmaxf(fmaxf(sv[3][0], sv[3][1]), fmaxf(sv[3][2], sv[3][3]));
      bm = fmaxf(fmaxf(a0, a1), fmaxf(a2, a3));
    }
    bm = fmaxf(bm, __shfl_xor(bm, 16));
    bm = fmaxf(bm, __shfl_xor(bm, 32));
    const int grow = __any(bm > mr + 8.f);
    float al = 1.f;
    if (grow) {
      const float mn = fmaxf(mr, bm);
      al = __builtin_amdgcn_exp2f(mr - mn);
      mr = mn;
    }
#pragma unroll
    for (int t = 0; t < 4; ++t)
#pragma unroll
      for (int r = 0; r < 4; ++r) sv[t][r] = __builtin_amdgcn_exp2f(sv[t][r] - mr);
    float rs;
    {
      const float a0 = (sv[0][0] + sv[0][1]) + (sv[0][2] + sv[0][3]);
      const float a1 = (sv[1][0] + sv[1][1]) + (sv[1][2] + sv[1][3]);
      const float a2 = (sv[2][0] + sv[2][1]) + (sv[2][2] + sv[2][3]);
      const float a3 = (sv[3][0] + sv[3][1]) + (sv[3][2] + sv[3][3]);
      rs = (a0 + a1) + (a2 + a3);
    }
    rs += __shfl_xor(rs, 16);
    rs += __shfl_xor(rs, 32);
    lr = lr * al + rs;
    if (grow) {
      float alq[4];
#pragma unroll
      for (int r = 0; r < 4; ++r) alq[r] = __shfl(al, lh * 4 + r);
#pragma unroll
      for (int dt = 0; dt < 4; ++dt)
#pragma unroll
        for (int r = 0; r < 4; ++r) acc[dt][r] *= alq[r];
    }

#pragma unroll
    for (int t = 0; t < 4; ++t) {
      uint2 u;
      u.x = cvt_pk_bf16(sv[t][0], sv[t][1]);
      u.y = cvt_pk_bf16(sv[t][2], sv[t][3]);
      *reinterpret_cast<uint2*>(&Ps[w][ln15 * 72 + t * 16 + lh * 4]) = u;
    }

    bf16x8 ap[2];
#pragma unroll
    for (int ch = 0; ch < 2; ++ch)
      ap[ch] = *reinterpret_cast<const bf16x8*>(&Ps[w][ln15 * 72 + ch * 32 + lh * 8]);
    __builtin_amdgcn_s_setprio(1);
#pragma unroll
    for (int dt = 0; dt < 4; ++dt) {
#pragma unroll
      for (int ch = 0; ch < 2; ++ch) {
        bf16x8 bv = *reinterpret_cast<const bf16x8*>(
            &Vs[s][(dt * 16 + ln15) * 64 + ((ch * 32 + lh * 8) ^ swz)]);
        acc[dt] = __builtin_amdgcn_mfma_f32_16x16x32_bf16(ap[ch], bv, acc[dt], 0, 0, 0);
      }
    }
    __builtin_amdgcn_s_setprio(0);
  }

  float lrq[4];
#pragma unroll
  for (int r = 0; r < 4; ++r) lrq[r] = 1.0f / __shfl(lr, lh * 4 + r);
  const int qrow = qb * 64 + w * 16 + lh * 4;
#pragma unroll
  for (int dt = 0; dt < 4; ++dt)
#pragma unroll
    for (int r = 0; r < 4; ++r)
      O[((size_t)b * SEQ + qrow + r) * DMODEL + h * 64 + dt * 16 + ln15] = f2bf(acc[dt][r] * lrq[r]);
}

extern "C" void kernel_launch(void* const* d_in, const int* in_sizes, int n_in,
                              void* d_out, int out_size, void* d_ws, size_t ws_size,
                              hipStream_t stream) {
  const float* x      = (const float*)d_in[0];
  const float* qkv_w  = (const float*)d_in[1];
  const float* proj_w = (const float*)d_in[2];
  const float* proj_b = (const float*)d_in[3];
  float* out = (float*)d_out;

  char* ws = (char*)d_ws;
  const size_t SZ_XB  = (size_t)MTOT * DMODEL * 2;   // x bf16; reused as attn-out bf16
  const size_t SZ_WQT = (size_t)NQKV * DMODEL * 2;
  const size_t SZ_WPT = (size_t)DMODEL * DMODEL * 2;
  const size_t SZ_QKV = (size_t)BB * NHEAD * SEQ * HDIM * 2;
  unsigned short* Xb  = (unsigned short*)ws;
  unsigned short* WqT = (unsigned short*)(ws + SZ_XB);
  unsigned short* WpT = (unsigned short*)(ws + SZ_XB + SZ_WQT);
  unsigned short* Qd  = (unsigned short*)(ws + SZ_XB + SZ_WQT + SZ_WPT);
  unsigned short* Kd  = (unsigned short*)(ws + SZ_XB + SZ_WQT + SZ_WPT + SZ_QKV);
  unsigned short* Vt  = (unsigned short*)(ws + SZ_XB + SZ_WQT + SZ_WPT + 2 * SZ_QKV);
  if (ws_size < SZ_XB + SZ_WQT + SZ_WPT + 3 * SZ_QKV) return;

  // 1) x -> bf16
  k_cvt_bf16<<<2048, 256, 0, stream>>>((const float4*)x, (ushort4*)Xb, MTOT * DMODEL / 4);
  // 2) weight transposes (f32 -> bf16, B^T layout)
  k_transpose_bf16<<<dim3(NQKV / 32, DMODEL / 32), 256, 0, stream>>>(qkv_w, WqT, DMODEL, NQKV);
  k_transpose_bf16<<<dim3(DMODEL / 32, DMODEL / 32), 256, 0, stream>>>(proj_w, WpT, DMODEL, DMODEL);
  // 3) QKV projection -> per-head Q (pre-scaled), K, V^T. 1152 blocks, XCD-swizzled.
  k_gemm_bt<1><<<(MTOT / 128) * (NQKV / 256), 256, 0, stream>>>(
      Xb, WqT, MTOT, NQKV, DMODEL, (MTOT / 128) * (NQKV / 256),
      nullptr, nullptr, Qd, Kd, Vt);
  // 4) fused attention -> Oattn (reuses Xb region)
  k_attn<<<BB * NHEAD * (SEQ / 64), 256, 0, stream>>>(Qd, Kd, Vt, Xb);
  // 5) output projection + bias -> f32 out. 384 blocks, XCD-swizzled.
  k_gemm_bt<0><<<(MTOT / 128) * (DMODEL / 256), 256, 0, stream>>>(
      Xb, WpT, MTOT, DMODEL, DMODEL, (MTOT / 128) * (DMODEL / 256),
      out, proj_b, nullptr, nullptr, nullptr);
}

// Round 8
// 215.989 us; speedup vs baseline: 1.7424x; 1.7424x over previous
//
#include <hip/hip_runtime.h>
#include <cstdint>
#include <cstddef>

typedef float f32x4 __attribute__((ext_vector_type(4)));
typedef __bf16 bf16x8 __attribute__((ext_vector_type(8)));

#define BB 16
#define SEQ 1024
#define DMODEL 768
#define NHEAD 12
#define HDIM 64
#define MTOT (BB * SEQ)
#define NQKV (3 * DMODEL)
#define NQK (2 * DMODEL)   // natural-layout Q|K row length
// 0.125 (hd^-0.5) * log2(e): QK^T then exp2 == exp(0.125 * qk)
#define QSCALE 0.18033688011112042f

static __device__ __forceinline__ unsigned short f2bf(float f) {
  unsigned int u = __builtin_bit_cast(unsigned int, f);
  u += 0x7fffu + ((u >> 16) & 1u);
  return (unsigned short)(u >> 16);
}

static __device__ __forceinline__ unsigned cvt_pk_bf16(float lo, float hi) {
  unsigned r;
  asm("v_cvt_pk_bf16_f32 %0, %1, %2" : "=v"(r) : "v"(lo), "v"(hi));
  return r;
}

static __device__ __forceinline__ void gload_lds16(const void* g, void* l) {
  __builtin_amdgcn_global_load_lds((__attribute__((address_space(1))) void*)g,
                                   (__attribute__((address_space(3))) void*)l,
                                   16, 0, 0);
}

// ---- prep: f32 -> bf16 convert (vectorized) ----
__global__ void k_cvt_bf16(const float4* __restrict__ in, ushort4* __restrict__ out, int n4) {
  int stride = gridDim.x * blockDim.x;
  for (int i = blockIdx.x * blockDim.x + threadIdx.x; i < n4; i += stride) {
    float4 v = in[i];
    ushort4 o;
    o.x = f2bf(v.x); o.y = f2bf(v.y); o.z = f2bf(v.z); o.w = f2bf(v.w);
    out[i] = o;
  }
}

// ---- prep: transpose f32 [R][C] -> bf16 [C][R]; cols < scaleN get *QSCALE ----
__global__ void k_transpose_bf16(const float* __restrict__ in, unsigned short* __restrict__ out,
                                 int R, int C, int scaleN) {
  __shared__ float tile[32][33];
  int tx = threadIdx.x & 31, ty = threadIdx.x >> 5;
  int c0 = blockIdx.x * 32, r0 = blockIdx.y * 32;
#pragma unroll
  for (int i = 0; i < 4; ++i)
    tile[ty + i * 8][tx] = in[(size_t)(r0 + ty + i * 8) * C + c0 + tx];
  __syncthreads();
#pragma unroll
  for (int i = 0; i < 4; ++i) {
    const int n = c0 + ty + i * 8;  // original column = output row
    float v = tile[tx][ty + i * 8];
    if (n < scaleN) v *= QSCALE;
    out[(size_t)n * R + r0 + tx] = f2bf(v);
  }
}

// ---- GEMM C[M,N] = A[M,K] * Bt[N,K]^T, bf16 in, f32 accum (R4 structure) ----
// 128(m) x 256(n) tile, BK=64, single-buffered, 2 barriers/K-tile, 4 waves each
// computing 64x128 (acc 4x8). T2 swizzle both-sides (rule 21).
// MODE 0: outF = C + bias (f32, natural).
// MODE 1: n < 1536 -> natural bf16 [m][1536] (Q|K, coalesced; Q pre-scaled via W);
//         n >= 1536 -> V^T packed ushort4 stores (r-loop is nr-contiguous).
template <int MODE>
__global__ __launch_bounds__(256, 2) void k_gemm_bt(
    const unsigned short* __restrict__ A, const unsigned short* __restrict__ Bt,
    int M, int N, int K,
    float* __restrict__ outF, const float* __restrict__ bias,
    unsigned short* __restrict__ QK, unsigned short* __restrict__ Vt) {
  __shared__ __align__(16) unsigned short As[128 * 64];  // 16 KB
  __shared__ __align__(16) unsigned short Bs[256 * 64];  // 32 KB
  const int tid = threadIdx.x;
  const int lane = tid & 63, wid = tid >> 6;
  const int ln15 = lane & 15, lh = lane >> 4;
  const int wr = wid >> 1, wc = wid & 1;
  const int m0 = blockIdx.x * 128, n0 = blockIdx.y * 256;
  f32x4 acc[4][8] = {};
  // staging: 1KB chunk = 8 rows x 128B; lane covers row (lane>>3), 16B block ((lane&7)^(lane>>3))
  const int srow = lane >> 3;
  const int sblk = ((lane & 7) ^ srow) * 8;
  // read-side swizzle: element offset ^= (row&7)<<3
  const int swz = (ln15 & 7) << 3;
  const int nk = K >> 6;

  for (int kt = 0; kt < nk; ++kt) {
    const int k0 = kt * 64;
#pragma unroll
    for (int c = 0; c < 4; ++c) {  // A: 16 chunks, wave takes 4
      const int ch = wid * 4 + c;
      const int row = ch * 8 + srow;
      gload_lds16(A + (size_t)(m0 + row) * K + k0 + sblk, &As[ch * 512]);
    }
#pragma unroll
    for (int c = 0; c < 8; ++c) {  // B: 32 chunks, wave takes 8
      const int ch = wid * 8 + c;
      const int row = ch * 8 + srow;
      gload_lds16(Bt + (size_t)(n0 + row) * K + k0 + sblk, &Bs[ch * 512]);
    }
    __syncthreads();
#pragma unroll
    for (int kk = 0; kk < 2; ++kk) {
      const int kc = kk * 32 + lh * 8;
      bf16x8 af[4], bfv[8];
#pragma unroll
      for (int mt = 0; mt < 4; ++mt)
        af[mt] = *reinterpret_cast<const bf16x8*>(
            &As[(wr * 64 + mt * 16 + ln15) * 64 + (kc ^ swz)]);
#pragma unroll
      for (int nn = 0; nn < 8; ++nn)
        bfv[nn] = *reinterpret_cast<const bf16x8*>(
            &Bs[(wc * 128 + nn * 16 + ln15) * 64 + (kc ^ swz)]);
#pragma unroll
      for (int mt = 0; mt < 4; ++mt)
#pragma unroll
        for (int nn = 0; nn < 8; ++nn)
          acc[mt][nn] = __builtin_amdgcn_mfma_f32_16x16x32_bf16(af[mt], bfv[nn], acc[mt][nn], 0, 0, 0);
    }
    __syncthreads();
  }

#pragma unroll
  for (int mt = 0; mt < 4; ++mt) {
#pragma unroll
    for (int nn = 0; nn < 8; ++nn) {
      const int nb = n0 + wc * 128 + nn * 16;  // tile-uniform n base (16-aligned)
      const int mb = m0 + wr * 64 + mt * 16 + lh * 4;
      if (MODE == 0) {
#pragma unroll
        for (int r = 0; r < 4; ++r)
          outF[(size_t)(mb + r) * N + nb + ln15] = acc[mt][nn][r] + bias[nb + ln15];
      } else if (nb < NQK) {
        // natural Q|K write: bf16 [m][1536], coalesced over ln15
#pragma unroll
        for (int r = 0; r < 4; ++r)
          QK[(size_t)(mb + r) * NQK + nb + ln15] = f2bf(acc[mt][nn][r]);
      } else {
        // V^T packed write: 4 consecutive nr in one ushort4
        const int rr = nb + ln15 - NQK;           // 0..767
        const int h = rr >> 6, d = rr & 63;
        const int b = mb >> 10, nr0 = mb & 1023;  // r=0 row; tile fits one batch row-block
        ushort4 u;
        u.x = f2bf(acc[mt][nn][0]); u.y = f2bf(acc[mt][nn][1]);
        u.z = f2bf(acc[mt][nn][2]); u.w = f2bf(acc[mt][nn][3]);
        *reinterpret_cast<ushort4*>(
            &Vt[(((size_t)b * NHEAD + h) * HDIM + d) * SEQ + nr0]) = u;
      }
    }
  }
}

// ---- fused flash attention, swapped-QK^T in-register softmax ----
// Q,K read from natural qkvQK [m][1536] (row stride NQK); V from Vt [bh][d][nr].
__global__ __launch_bounds__(256) void k_attn(
    const unsigned short* __restrict__ QKn, const unsigned short* __restrict__ Vt,
    unsigned short* __restrict__ O) {
  __shared__ __align__(16) unsigned short Ks[64 * 64];      // [kpos][d], swizzled
  __shared__ __align__(16) unsigned short Vs[64 * 64];      // [d][kpos], swizzled
  __shared__ __align__(16) unsigned short Ps[4][16 * 72];   // per-wave P [q][kpos], stride 72
  const int tid = threadIdx.x;
  const int lane = tid & 63, w = tid >> 6;
  const int ln15 = lane & 15, lh = lane >> 4;
  const int bid = blockIdx.x;
  const int qb = bid & 15;
  const int h = (bid >> 4) % NHEAD;
  const int b = bid / (16 * NHEAD);
  const size_t bh = (size_t)(b * NHEAD + h);
  // Q rows m = b*1024 + qb*64 + w*16 + ln15, cols h*64 + ...
  const unsigned short* Qbase = QKn + (size_t)(b * SEQ + qb * 64 + w * 16) * NQK + h * HDIM;
  const unsigned short* Kbase = QKn + (size_t)(b * SEQ) * NQK + DMODEL + h * HDIM;
  const unsigned short* Vbase = Vt + bh * HDIM * SEQ;

  const int srow = lane >> 3;
  const int sblk = ((lane & 7) ^ srow) * 8;
  const int swz = (ln15 & 7) << 3;

  bf16x8 aq[2];
#pragma unroll
  for (int ch = 0; ch < 2; ++ch)
    aq[ch] = *reinterpret_cast<const bf16x8*>(Qbase + (size_t)ln15 * NQK + ch * 32 + lh * 8);

  f32x4 acc[4] = {};
  float mr = -1e30f, lr = 0.f;

  for (int kb = 0; kb < SEQ / 64; ++kb) {
#pragma unroll
    for (int c2 = 0; c2 < 2; ++c2) {
      const int c = w * 2 + c2;
      const int row = c * 8 + srow;
      gload_lds16(Kbase + (size_t)(kb * 64 + row) * NQK + sblk, &Ks[c * 512]);
      gload_lds16(Vbase + (size_t)row * SEQ + kb * 64 + sblk, &Vs[c * 512]);
    }
    __syncthreads();

    f32x4 s[4] = {};
    __builtin_amdgcn_s_setprio(1);
#pragma unroll
    for (int t = 0; t < 4; ++t) {
#pragma unroll
      for (int ch = 0; ch < 2; ++ch) {
        bf16x8 bk = *reinterpret_cast<const bf16x8*>(
            &Ks[(t * 16 + ln15) * 64 + ((ch * 32 + lh * 8) ^ swz)]);
        s[t] = __builtin_amdgcn_mfma_f32_16x16x32_bf16(bk, aq[ch], s[t], 0, 0, 0);
      }
    }
    __builtin_amdgcn_s_setprio(0);

    float bm;
    {
      const float a0 = fmaxf(fmaxf(s[0][0], s[0][1]), fmaxf(s[0][2], s[0][3]));
      const float a1 = fmaxf(fmaxf(s[1][0], s[1][1]), fmaxf(s[1][2], s[1][3]));
      const float a2 = fmaxf(fmaxf(s[2][0], s[2][1]), fmaxf(s[2][2], s[2][3]));
      const float a3 = fmaxf(fmaxf(s[3][0], s[3][1]), fmaxf(s[3][2], s[3][3]));
      bm = fmaxf(fmaxf(a0, a1), fmaxf(a2, a3));
    }
    bm = fmaxf(bm, __shfl_xor(bm, 16));
    bm = fmaxf(bm, __shfl_xor(bm, 32));
    const int grow = __any(bm > mr + 8.f);
    float al = 1.f;
    if (grow) {
      const float mn = fmaxf(mr, bm);
      al = __builtin_amdgcn_exp2f(mr - mn);
      mr = mn;
    }
#pragma unroll
    for (int t = 0; t < 4; ++t)
#pragma unroll
      for (int r = 0; r < 4; ++r) s[t][r] = __builtin_amdgcn_exp2f(s[t][r] - mr);
    float rs;
    {
      const float a0 = (s[0][0] + s[0][1]) + (s[0][2] + s[0][3]);
      const float a1 = (s[1][0] + s[1][1]) + (s[1][2] + s[1][3]);
      const float a2 = (s[2][0] + s[2][1]) + (s[2][2] + s[2][3]);
      const float a3 = (s[3][0] + s[3][1]) + (s[3][2] + s[3][3]);
      rs = (a0 + a1) + (a2 + a3);
    }
    rs += __shfl_xor(rs, 16);
    rs += __shfl_xor(rs, 32);
    lr = lr * al + rs;
    if (grow) {
      float alq[4];
#pragma unroll
      for (int r = 0; r < 4; ++r) alq[r] = __shfl(al, lh * 4 + r);
#pragma unroll
      for (int dt = 0; dt < 4; ++dt)
#pragma unroll
        for (int r = 0; r < 4; ++r) acc[dt][r] *= alq[r];
    }

#pragma unroll
    for (int t = 0; t < 4; ++t) {
      uint2 u;
      u.x = cvt_pk_bf16(s[t][0], s[t][1]);
      u.y = cvt_pk_bf16(s[t][2], s[t][3]);
      *reinterpret_cast<uint2*>(&Ps[w][ln15 * 72 + t * 16 + lh * 4]) = u;
    }

    bf16x8 ap[2];
#pragma unroll
    for (int ch = 0; ch < 2; ++ch)
      ap[ch] = *reinterpret_cast<const bf16x8*>(&Ps[w][ln15 * 72 + ch * 32 + lh * 8]);
    __builtin_amdgcn_s_setprio(1);
#pragma unroll
    for (int dt = 0; dt < 4; ++dt) {
#pragma unroll
      for (int ch = 0; ch < 2; ++ch) {
        bf16x8 bv = *reinterpret_cast<const bf16x8*>(
            &Vs[(dt * 16 + ln15) * 64 + ((ch * 32 + lh * 8) ^ swz)]);
        acc[dt] = __builtin_amdgcn_mfma_f32_16x16x32_bf16(ap[ch], bv, acc[dt], 0, 0, 0);
      }
    }
    __builtin_amdgcn_s_setprio(0);
    __syncthreads();
  }

  float lrq[4];
#pragma unroll
  for (int r = 0; r < 4; ++r) lrq[r] = 1.0f / __shfl(lr, lh * 4 + r);
  const int qrow = qb * 64 + w * 16 + lh * 4;
#pragma unroll
  for (int dt = 0; dt < 4; ++dt)
#pragma unroll
    for (int r = 0; r < 4; ++r)
      O[((size_t)b * SEQ + qrow + r) * DMODEL + h * 64 + dt * 16 + ln15] = f2bf(acc[dt][r] * lrq[r]);
}

extern "C" void kernel_launch(void* const* d_in, const int* in_sizes, int n_in,
                              void* d_out, int out_size, void* d_ws, size_t ws_size,
                              hipStream_t stream) {
  const float* x      = (const float*)d_in[0];
  const float* qkv_w  = (const float*)d_in[1];
  const float* proj_w = (const float*)d_in[2];
  const float* proj_b = (const float*)d_in[3];
  float* out = (float*)d_out;

  char* ws = (char*)d_ws;
  const size_t SZ_XB   = (size_t)MTOT * DMODEL * 2;   // x bf16; reused as attn-out bf16
  const size_t SZ_WQT  = (size_t)NQKV * DMODEL * 2;
  const size_t SZ_WPT  = (size_t)DMODEL * DMODEL * 2;
  const size_t SZ_QK   = (size_t)MTOT * NQK * 2;      // natural Q|K [m][1536]
  const size_t SZ_VT   = (size_t)BB * NHEAD * HDIM * SEQ * 2;
  unsigned short* Xb   = (unsigned short*)ws;
  unsigned short* WqT  = (unsigned short*)(ws + SZ_XB);
  unsigned short* WpT  = (unsigned short*)(ws + SZ_XB + SZ_WQT);
  unsigned short* QKn  = (unsigned short*)(ws + SZ_XB + SZ_WQT + SZ_WPT);
  unsigned short* Vt   = (unsigned short*)(ws + SZ_XB + SZ_WQT + SZ_WPT + SZ_QK);
  if (ws_size < SZ_XB + SZ_WQT + SZ_WPT + SZ_QK + SZ_VT) return;

  // 1) x -> bf16
  k_cvt_bf16<<<2048, 256, 0, stream>>>((const float4*)x, (ushort4*)Xb, MTOT * DMODEL / 4);
  // 2) weight transposes (f32 -> bf16, B^T layout); Q-columns pre-scaled by QSCALE
  k_transpose_bf16<<<dim3(NQKV / 32, DMODEL / 32), 256, 0, stream>>>(qkv_w, WqT, DMODEL, NQKV, DMODEL);
  k_transpose_bf16<<<dim3(DMODEL / 32, DMODEL / 32), 256, 0, stream>>>(proj_w, WpT, DMODEL, DMODEL, 0);
  // 3) QKV projection -> natural Q|K [m][1536] + packed V^T
  k_gemm_bt<1><<<dim3(MTOT / 128, NQKV / 256), 256, 0, stream>>>(
      Xb, WqT, MTOT, NQKV, DMODEL, nullptr, nullptr, QKn, Vt);
  // 4) fused attention -> Oattn (reuses Xb region; Xb is dead after step 3)
  k_attn<<<BB * NHEAD * (SEQ / 64), 256, 0, stream>>>(QKn, Vt, Xb);
  // 5) output projection + bias -> f32 out
  k_gemm_bt<0><<<dim3(MTOT / 128, DMODEL / 256), 256, 0, stream>>>(
      Xb, WpT, MTOT, DMODEL, DMODEL, out, proj_b, nullptr, nullptr);
}

// Round 9
// 202.468 us; speedup vs baseline: 1.8588x; 1.0668x over previous
//
#include <hip/hip_runtime.h>
#include <cstdint>
#include <cstddef>

typedef float f32x4 __attribute__((ext_vector_type(4)));
typedef __bf16 bf16x8 __attribute__((ext_vector_type(8)));

#define BB 16
#define SEQ 1024
#define DMODEL 768
#define NHEAD 12
#define HDIM 64
#define MTOT (BB * SEQ)
#define NQKV (3 * DMODEL)
#define NQK (2 * DMODEL)   // natural-layout Q|K row length
// 0.125 (hd^-0.5) * log2(e): QK^T then exp2 == exp(0.125 * qk)
#define QSCALE 0.18033688011112042f

static __device__ __forceinline__ unsigned short f2bf(float f) {
  unsigned int u = __builtin_bit_cast(unsigned int, f);
  u += 0x7fffu + ((u >> 16) & 1u);
  return (unsigned short)(u >> 16);
}

static __device__ __forceinline__ unsigned cvt_pk_bf16(float lo, float hi) {
  unsigned r;
  asm("v_cvt_pk_bf16_f32 %0, %1, %2" : "=v"(r) : "v"(lo), "v"(hi));
  return r;
}

static __device__ __forceinline__ void gload_lds16(const void* g, void* l) {
  __builtin_amdgcn_global_load_lds((__attribute__((address_space(1))) void*)g,
                                   (__attribute__((address_space(3))) void*)l,
                                   16, 0, 0);
}

// ---- prep: f32 -> bf16 convert (vectorized) ----
__global__ void k_cvt_bf16(const float4* __restrict__ in, ushort4* __restrict__ out, int n4) {
  int stride = gridDim.x * blockDim.x;
  for (int i = blockIdx.x * blockDim.x + threadIdx.x; i < n4; i += stride) {
    float4 v = in[i];
    ushort4 o;
    o.x = f2bf(v.x); o.y = f2bf(v.y); o.z = f2bf(v.z); o.w = f2bf(v.w);
    out[i] = o;
  }
}

// ---- prep: transpose f32 [R][C] -> bf16 [C][R]; cols < scaleN get *QSCALE ----
__global__ void k_transpose_bf16(const float* __restrict__ in, unsigned short* __restrict__ out,
                                 int R, int C, int scaleN) {
  __shared__ float tile[32][33];
  int tx = threadIdx.x & 31, ty = threadIdx.x >> 5;
  int c0 = blockIdx.x * 32, r0 = blockIdx.y * 32;
#pragma unroll
  for (int i = 0; i < 4; ++i)
    tile[ty + i * 8][tx] = in[(size_t)(r0 + ty + i * 8) * C + c0 + tx];
  __syncthreads();
#pragma unroll
  for (int i = 0; i < 4; ++i) {
    const int n = c0 + ty + i * 8;  // original column = output row
    float v = tile[tx][ty + i * 8];
    if (n < scaleN) v *= QSCALE;
    out[(size_t)n * R + r0 + tx] = f2bf(v);
  }
}

// ---- GEMM C[M,N] = A[M,K] * Bt[N,K]^T, bf16 in, f32 accum (R4 structure) ----
// 128(m) x 256(n) tile, BK=64, single-buffered, 2 barriers/K-tile, 4 waves each
// computing 64x128 (acc 4x8). T2 swizzle both-sides (rule 21).
// MODE 0: outF = C + bias (f32, natural).
// MODE 1: n < 1536 -> natural bf16 [m][1536] (Q|K, coalesced; Q pre-scaled via W);
//         n >= 1536 -> V^T packed ushort4 stores (r-loop is nr-contiguous).
template <int MODE>
__global__ __launch_bounds__(256, 2) void k_gemm_bt(
    const unsigned short* __restrict__ A, const unsigned short* __restrict__ Bt,
    int M, int N, int K,
    float* __restrict__ outF, const float* __restrict__ bias,
    unsigned short* __restrict__ QK, unsigned short* __restrict__ Vt) {
  __shared__ __align__(16) unsigned short As[128 * 64];  // 16 KB
  __shared__ __align__(16) unsigned short Bs[256 * 64];  // 32 KB
  const int tid = threadIdx.x;
  const int lane = tid & 63, wid = tid >> 6;
  const int ln15 = lane & 15, lh = lane >> 4;
  const int wr = wid >> 1, wc = wid & 1;
  const int m0 = blockIdx.x * 128, n0 = blockIdx.y * 256;
  f32x4 acc[4][8] = {};
  // staging: 1KB chunk = 8 rows x 128B; lane covers row (lane>>3), 16B block ((lane&7)^(lane>>3))
  const int srow = lane >> 3;
  const int sblk = ((lane & 7) ^ srow) * 8;
  // read-side swizzle: element offset ^= (row&7)<<3
  const int swz = (ln15 & 7) << 3;
  const int nk = K >> 6;

  for (int kt = 0; kt < nk; ++kt) {
    const int k0 = kt * 64;
#pragma unroll
    for (int c = 0; c < 4; ++c) {  // A: 16 chunks, wave takes 4
      const int ch = wid * 4 + c;
      const int row = ch * 8 + srow;
      gload_lds16(A + (size_t)(m0 + row) * K + k0 + sblk, &As[ch * 512]);
    }
#pragma unroll
    for (int c = 0; c < 8; ++c) {  // B: 32 chunks, wave takes 8
      const int ch = wid * 8 + c;
      const int row = ch * 8 + srow;
      gload_lds16(Bt + (size_t)(n0 + row) * K + k0 + sblk, &Bs[ch * 512]);
    }
    __syncthreads();
#pragma unroll
    for (int kk = 0; kk < 2; ++kk) {
      const int kc = kk * 32 + lh * 8;
      bf16x8 af[4], bfv[8];
#pragma unroll
      for (int mt = 0; mt < 4; ++mt)
        af[mt] = *reinterpret_cast<const bf16x8*>(
            &As[(wr * 64 + mt * 16 + ln15) * 64 + (kc ^ swz)]);
#pragma unroll
      for (int nn = 0; nn < 8; ++nn)
        bfv[nn] = *reinterpret_cast<const bf16x8*>(
            &Bs[(wc * 128 + nn * 16 + ln15) * 64 + (kc ^ swz)]);
#pragma unroll
      for (int mt = 0; mt < 4; ++mt)
#pragma unroll
        for (int nn = 0; nn < 8; ++nn)
          acc[mt][nn] = __builtin_amdgcn_mfma_f32_16x16x32_bf16(af[mt], bfv[nn], acc[mt][nn], 0, 0, 0);
    }
    __syncthreads();
  }

#pragma unroll
  for (int mt = 0; mt < 4; ++mt) {
#pragma unroll
    for (int nn = 0; nn < 8; ++nn) {
      const int nb = n0 + wc * 128 + nn * 16;  // tile-uniform n base (16-aligned)
      const int mb = m0 + wr * 64 + mt * 16 + lh * 4;
      if (MODE == 0) {
#pragma unroll
        for (int r = 0; r < 4; ++r)
          outF[(size_t)(mb + r) * N + nb + ln15] = acc[mt][nn][r] + bias[nb + ln15];
      } else if (nb < NQK) {
        // natural Q|K write: bf16 [m][1536], coalesced over ln15
#pragma unroll
        for (int r = 0; r < 4; ++r)
          QK[(size_t)(mb + r) * NQK + nb + ln15] = f2bf(acc[mt][nn][r]);
      } else {
        // V^T packed write: 4 consecutive nr in one ushort4
        const int rr = nb + ln15 - NQK;           // 0..767
        const int h = rr >> 6, d = rr & 63;
        const int b = mb >> 10, nr0 = mb & 1023;  // r=0 row; tile fits one batch row-block
        ushort4 u;
        u.x = f2bf(acc[mt][nn][0]); u.y = f2bf(acc[mt][nn][1]);
        u.z = f2bf(acc[mt][nn][2]); u.w = f2bf(acc[mt][nn][3]);
        *reinterpret_cast<ushort4*>(
            &Vt[(((size_t)b * NHEAD + h) * HDIM + d) * SEQ + nr0]) = u;
      }
    }
  }
}

// ---- fused flash attention, swapped-QK^T in-register softmax ----
// QBLK=128 q-rows/block, 8 waves x 16 rows: one K/V staging serves 2x the work
// vs QBLK=64 (halved staging traffic + barriers). XCD-grouping swizzle: all 8
// qb-blocks of a head get consecutive sid on ONE XCD (o&7 = chunk) -> K/V is
// fetched ~once per XCD instead of 8x (T1 on the real sharing structure).
__global__ __launch_bounds__(512) void k_attn(
    const unsigned short* __restrict__ QKn, const unsigned short* __restrict__ Vt,
    unsigned short* __restrict__ O) {
  __shared__ __align__(16) unsigned short Ks[64 * 64];      // [kpos][d], swizzled
  __shared__ __align__(16) unsigned short Vs[64 * 64];      // [d][kpos], swizzled
  __shared__ __align__(16) unsigned short Ps[8][16 * 72];   // per-wave P [q][kpos], stride 72
  const int tid = threadIdx.x;
  const int lane = tid & 63, w = tid >> 6;
  const int ln15 = lane & 15, lh = lane >> 4;
  // XCD-grouping: 1536 blocks, 192 per XCD-chunk; qb fastest within a head
  const int o = blockIdx.x;
  const int sid = (o & 7) * 192 + (o >> 3);
  const int qb = sid & 7;
  const int bhid = sid >> 3;
  const int h = bhid % NHEAD;
  const int b = bhid / NHEAD;
  const size_t bh = (size_t)(b * NHEAD + h);
  const unsigned short* Qbase = QKn + (size_t)(b * SEQ + qb * 128 + w * 16) * NQK + h * HDIM;
  const unsigned short* Kbase = QKn + (size_t)(b * SEQ) * NQK + DMODEL + h * HDIM;
  const unsigned short* Vbase = Vt + bh * HDIM * SEQ;

  const int srow = lane >> 3;
  const int sblk = ((lane & 7) ^ srow) * 8;
  const int swz = (ln15 & 7) << 3;

  bf16x8 aq[2];
#pragma unroll
  for (int ch = 0; ch < 2; ++ch)
    aq[ch] = *reinterpret_cast<const bf16x8*>(Qbase + (size_t)ln15 * NQK + ch * 32 + lh * 8);

  f32x4 acc[4] = {};
  float mr = -1e30f, lr = 0.f;

  for (int kb = 0; kb < SEQ / 64; ++kb) {
    // staging: 8 K-chunks + 8 V-chunks; wave w takes chunk w of each
    {
      const int row = w * 8 + srow;
      gload_lds16(Kbase + (size_t)(kb * 64 + row) * NQK + sblk, &Ks[w * 512]);
      gload_lds16(Vbase + (size_t)row * SEQ + kb * 64 + sblk, &Vs[w * 512]);
    }
    __syncthreads();

    f32x4 s[4] = {};
    __builtin_amdgcn_s_setprio(1);
#pragma unroll
    for (int t = 0; t < 4; ++t) {
#pragma unroll
      for (int ch = 0; ch < 2; ++ch) {
        bf16x8 bk = *reinterpret_cast<const bf16x8*>(
            &Ks[(t * 16 + ln15) * 64 + ((ch * 32 + lh * 8) ^ swz)]);
        s[t] = __builtin_amdgcn_mfma_f32_16x16x32_bf16(bk, aq[ch], s[t], 0, 0, 0);
      }
    }
    __builtin_amdgcn_s_setprio(0);

    float bm;
    {
      const float a0 = fmaxf(fmaxf(s[0][0], s[0][1]), fmaxf(s[0][2], s[0][3]));
      const float a1 = fmaxf(fmaxf(s[1][0], s[1][1]), fmaxf(s[1][2], s[1][3]));
      const float a2 = fmaxf(fmaxf(s[2][0], s[2][1]), fmaxf(s[2][2], s[2][3]));
      const float a3 = fmaxf(fmaxf(s[3][0], s[3][1]), fmaxf(s[3][2], s[3][3]));
      bm = fmaxf(fmaxf(a0, a1), fmaxf(a2, a3));
    }
    bm = fmaxf(bm, __shfl_xor(bm, 16));
    bm = fmaxf(bm, __shfl_xor(bm, 32));
    const int grow = __any(bm > mr + 8.f);
    float al = 1.f;
    if (grow) {
      const float mn = fmaxf(mr, bm);
      al = __builtin_amdgcn_exp2f(mr - mn);
      mr = mn;
    }
#pragma unroll
    for (int t = 0; t < 4; ++t)
#pragma unroll
      for (int r = 0; r < 4; ++r) s[t][r] = __builtin_amdgcn_exp2f(s[t][r] - mr);
    float rs;
    {
      const float a0 = (s[0][0] + s[0][1]) + (s[0][2] + s[0][3]);
      const float a1 = (s[1][0] + s[1][1]) + (s[1][2] + s[1][3]);
      const float a2 = (s[2][0] + s[2][1]) + (s[2][2] + s[2][3]);
      const float a3 = (s[3][0] + s[3][1]) + (s[3][2] + s[3][3]);
      rs = (a0 + a1) + (a2 + a3);
    }
    rs += __shfl_xor(rs, 16);
    rs += __shfl_xor(rs, 32);
    lr = lr * al + rs;
    if (grow) {
      float alq[4];
#pragma unroll
      for (int r = 0; r < 4; ++r) alq[r] = __shfl(al, lh * 4 + r);
#pragma unroll
      for (int dt = 0; dt < 4; ++dt)
#pragma unroll
        for (int r = 0; r < 4; ++r) acc[dt][r] *= alq[r];
    }

#pragma unroll
    for (int t = 0; t < 4; ++t) {
      uint2 u;
      u.x = cvt_pk_bf16(s[t][0], s[t][1]);
      u.y = cvt_pk_bf16(s[t][2], s[t][3]);
      *reinterpret_cast<uint2*>(&Ps[w][ln15 * 72 + t * 16 + lh * 4]) = u;
    }

    bf16x8 ap[2];
#pragma unroll
    for (int ch = 0; ch < 2; ++ch)
      ap[ch] = *reinterpret_cast<const bf16x8*>(&Ps[w][ln15 * 72 + ch * 32 + lh * 8]);
    __builtin_amdgcn_s_setprio(1);
#pragma unroll
    for (int dt = 0; dt < 4; ++dt) {
#pragma unroll
      for (int ch = 0; ch < 2; ++ch) {
        bf16x8 bv = *reinterpret_cast<const bf16x8*>(
            &Vs[(dt * 16 + ln15) * 64 + ((ch * 32 + lh * 8) ^ swz)]);
        acc[dt] = __builtin_amdgcn_mfma_f32_16x16x32_bf16(ap[ch], bv, acc[dt], 0, 0, 0);
      }
    }
    __builtin_amdgcn_s_setprio(0);
    __syncthreads();
  }

  float lrq[4];
#pragma unroll
  for (int r = 0; r < 4; ++r) lrq[r] = 1.0f / __shfl(lr, lh * 4 + r);
  const int qrow = qb * 128 + w * 16 + lh * 4;
#pragma unroll
  for (int dt = 0; dt < 4; ++dt)
#pragma unroll
    for (int r = 0; r < 4; ++r)
      O[((size_t)b * SEQ + qrow + r) * DMODEL + h * 64 + dt * 16 + ln15] = f2bf(acc[dt][r] * lrq[r]);
}

extern "C" void kernel_launch(void* const* d_in, const int* in_sizes, int n_in,
                              void* d_out, int out_size, void* d_ws, size_t ws_size,
                              hipStream_t stream) {
  const float* x      = (const float*)d_in[0];
  const float* qkv_w  = (const float*)d_in[1];
  const float* proj_w = (const float*)d_in[2];
  const float* proj_b = (const float*)d_in[3];
  float* out = (float*)d_out;

  char* ws = (char*)d_ws;
  const size_t SZ_XB   = (size_t)MTOT * DMODEL * 2;   // x bf16; reused as attn-out bf16
  const size_t SZ_WQT  = (size_t)NQKV * DMODEL * 2;
  const size_t SZ_WPT  = (size_t)DMODEL * DMODEL * 2;
  const size_t SZ_QK   = (size_t)MTOT * NQK * 2;      // natural Q|K [m][1536]
  const size_t SZ_VT   = (size_t)BB * NHEAD * HDIM * SEQ * 2;
  unsigned short* Xb   = (unsigned short*)ws;
  unsigned short* WqT  = (unsigned short*)(ws + SZ_XB);
  unsigned short* WpT  = (unsigned short*)(ws + SZ_XB + SZ_WQT);
  unsigned short* QKn  = (unsigned short*)(ws + SZ_XB + SZ_WQT + SZ_WPT);
  unsigned short* Vt   = (unsigned short*)(ws + SZ_XB + SZ_WQT + SZ_WPT + SZ_QK);
  if (ws_size < SZ_XB + SZ_WQT + SZ_WPT + SZ_QK + SZ_VT) return;

  // 1) x -> bf16
  k_cvt_bf16<<<2048, 256, 0, stream>>>((const float4*)x, (ushort4*)Xb, MTOT * DMODEL / 4);
  // 2) weight transposes (f32 -> bf16, B^T layout); Q-columns pre-scaled by QSCALE
  k_transpose_bf16<<<dim3(NQKV / 32, DMODEL / 32), 256, 0, stream>>>(qkv_w, WqT, DMODEL, NQKV, DMODEL);
  k_transpose_bf16<<<dim3(DMODEL / 32, DMODEL / 32), 256, 0, stream>>>(proj_w, WpT, DMODEL, DMODEL, 0);
  // 3) QKV projection -> natural Q|K [m][1536] + packed V^T
  k_gemm_bt<1><<<dim3(MTOT / 128, NQKV / 256), 256, 0, stream>>>(
      Xb, WqT, MTOT, NQKV, DMODEL, nullptr, nullptr, QKn, Vt);
  // 4) fused attention -> Oattn (reuses Xb region; Xb is dead after step 3)
  k_attn<<<BB * NHEAD * 8, 512, 0, stream>>>(QKn, Vt, Xb);
  // 5) output projection + bias -> f32 out
  k_gemm_bt<0><<<dim3(MTOT / 128, DMODEL / 256), 256, 0, stream>>>(
      Xb, WpT, MTOT, DMODEL, DMODEL, out, proj_b, nullptr, nullptr);
}

// Round 10
// 186.120 us; speedup vs baseline: 2.0220x; 1.0878x over previous
//
#include <hip/hip_runtime.h>
#include <cstdint>
#include <cstddef>

typedef float f32x4 __attribute__((ext_vector_type(4)));
typedef __bf16 bf16x8 __attribute__((ext_vector_type(8)));

#define BB 16
#define SEQ 1024
#define DMODEL 768
#define NHEAD 12
#define HDIM 64
#define MTOT (BB * SEQ)
#define NQKV (3 * DMODEL)
#define NQK (2 * DMODEL)   // natural-layout Q|K row length
// 0.125 (hd^-0.5) * log2(e): QK^T then exp2 == exp(0.125 * qk)
#define QSCALE 0.18033688011112042f

static __device__ __forceinline__ unsigned short f2bf(float f) {
  unsigned int u = __builtin_bit_cast(unsigned int, f);
  u += 0x7fffu + ((u >> 16) & 1u);
  return (unsigned short)(u >> 16);
}

static __device__ __forceinline__ unsigned cvt_pk_bf16(float lo, float hi) {
  unsigned r;
  asm("v_cvt_pk_bf16_f32 %0, %1, %2" : "=v"(r) : "v"(lo), "v"(hi));
  return r;
}

static __device__ __forceinline__ void gload_lds16(const void* g, void* l) {
  __builtin_amdgcn_global_load_lds((__attribute__((address_space(1))) void*)g,
                                   (__attribute__((address_space(3))) void*)l,
                                   16, 0, 0);
}

// ---- prep: f32 -> bf16 convert (vectorized) ----
__global__ void k_cvt_bf16(const float4* __restrict__ in, ushort4* __restrict__ out, int n4) {
  int stride = gridDim.x * blockDim.x;
  for (int i = blockIdx.x * blockDim.x + threadIdx.x; i < n4; i += stride) {
    float4 v = in[i];
    ushort4 o;
    o.x = f2bf(v.x); o.y = f2bf(v.y); o.z = f2bf(v.z); o.w = f2bf(v.w);
    out[i] = o;
  }
}

// ---- prep: transpose f32 [R][C] -> bf16 [C][R]; cols < scaleN get *QSCALE ----
__global__ void k_transpose_bf16(const float* __restrict__ in, unsigned short* __restrict__ out,
                                 int R, int C, int scaleN) {
  __shared__ float tile[32][33];
  int tx = threadIdx.x & 31, ty = threadIdx.x >> 5;
  int c0 = blockIdx.x * 32, r0 = blockIdx.y * 32;
#pragma unroll
  for (int i = 0; i < 4; ++i)
    tile[ty + i * 8][tx] = in[(size_t)(r0 + ty + i * 8) * C + c0 + tx];
  __syncthreads();
#pragma unroll
  for (int i = 0; i < 4; ++i) {
    const int n = c0 + ty + i * 8;  // original column = output row
    float v = tile[tx][ty + i * 8];
    if (n < scaleN) v *= QSCALE;
    out[(size_t)n * R + r0 + tx] = f2bf(v);
  }
}

// ---- GEMM C[M,N] = A[M,K] * Bt[N,K]^T, bf16 in, f32 accum ----
// m97 geometry: 128x128 tile, BK=64 single-buffered (32 KB LDS), 2 barriers per
// K-step, 4 waves each computing 64x64 (acc 4x4 = 64 AGPR) -> light registers,
// __launch_bounds__(256,3) -> 3 blocks/CU (12 waves) for latency hiding via TLP.
// T2 swizzle both-sides (rule 21): linear LDS dest for global_load_lds, global
// source carries the involution (16B block ^= row&7), reads XOR the same bits.
// MODE 0: outF = C + bias (f32, natural).
// MODE 1: n < 1536 -> natural bf16 [m][1536] (Q|K, coalesced; Q pre-scaled via W);
//         n >= 1536 -> V^T packed ushort4 stores (r-loop is nr-contiguous).
template <int MODE>
__global__ __launch_bounds__(256, 3) void k_gemm_bt(
    const unsigned short* __restrict__ A, const unsigned short* __restrict__ Bt,
    int M, int N, int K,
    float* __restrict__ outF, const float* __restrict__ bias,
    unsigned short* __restrict__ QK, unsigned short* __restrict__ Vt) {
  __shared__ __align__(16) unsigned short As[128 * 64];  // 16 KB
  __shared__ __align__(16) unsigned short Bs[128 * 64];  // 16 KB
  const int tid = threadIdx.x;
  const int lane = tid & 63, wid = tid >> 6;
  const int ln15 = lane & 15, lh = lane >> 4;
  const int wr = wid >> 1, wc = wid & 1;
  const int m0 = blockIdx.x * 128, n0 = blockIdx.y * 128;
  f32x4 acc[4][4] = {};
  // staging: 1KB chunk = 8 rows x 128B; lane covers row (lane>>3), 16B block ((lane&7)^(lane>>3))
  const int srow = lane >> 3;
  const int sblk = ((lane & 7) ^ srow) * 8;
  // read-side swizzle: element offset ^= (row&7)<<3
  const int swz = (ln15 & 7) << 3;
  const int nk = K >> 6;

  for (int kt = 0; kt < nk; ++kt) {
    const int k0 = kt * 64;
#pragma unroll
    for (int c = 0; c < 4; ++c) {  // A,B: 16 chunks each, wave takes 4+4
      const int ch = wid * 4 + c;
      const int row = ch * 8 + srow;
      gload_lds16(A + (size_t)(m0 + row) * K + k0 + sblk, &As[ch * 512]);
      gload_lds16(Bt + (size_t)(n0 + row) * K + k0 + sblk, &Bs[ch * 512]);
    }
    __syncthreads();
#pragma unroll
    for (int kk = 0; kk < 2; ++kk) {
      const int kc = kk * 32 + lh * 8;
      bf16x8 af[4], bfv[4];
#pragma unroll
      for (int mt = 0; mt < 4; ++mt)
        af[mt] = *reinterpret_cast<const bf16x8*>(
            &As[(wr * 64 + mt * 16 + ln15) * 64 + (kc ^ swz)]);
#pragma unroll
      for (int nn = 0; nn < 4; ++nn)
        bfv[nn] = *reinterpret_cast<const bf16x8*>(
            &Bs[(wc * 64 + nn * 16 + ln15) * 64 + (kc ^ swz)]);
#pragma unroll
      for (int mt = 0; mt < 4; ++mt)
#pragma unroll
        for (int nn = 0; nn < 4; ++nn)
          acc[mt][nn] = __builtin_amdgcn_mfma_f32_16x16x32_bf16(af[mt], bfv[nn], acc[mt][nn], 0, 0, 0);
    }
    __syncthreads();
  }

#pragma unroll
  for (int mt = 0; mt < 4; ++mt) {
#pragma unroll
    for (int nn = 0; nn < 4; ++nn) {
      const int nb = n0 + wc * 64 + nn * 16;   // wave-uniform n base (16-aligned)
      const int mb = m0 + wr * 64 + mt * 16 + lh * 4;
      if (MODE == 0) {
#pragma unroll
        for (int r = 0; r < 4; ++r)
          outF[(size_t)(mb + r) * N + nb + ln15] = acc[mt][nn][r] + bias[nb + ln15];
      } else if (nb < NQK) {
        // natural Q|K write: bf16 [m][1536], coalesced over ln15
#pragma unroll
        for (int r = 0; r < 4; ++r)
          QK[(size_t)(mb + r) * NQK + nb + ln15] = f2bf(acc[mt][nn][r]);
      } else {
        // V^T packed write: 4 consecutive nr in one ushort4
        const int rr = nb + ln15 - NQK;           // 0..767
        const int h = rr >> 6, d = rr & 63;
        const int b = mb >> 10, nr0 = mb & 1023;  // tile fits one batch row-block
        ushort4 u;
        u.x = f2bf(acc[mt][nn][0]); u.y = f2bf(acc[mt][nn][1]);
        u.z = f2bf(acc[mt][nn][2]); u.w = f2bf(acc[mt][nn][3]);
        *reinterpret_cast<ushort4*>(
            &Vt[(((size_t)b * NHEAD + h) * HDIM + d) * SEQ + nr0]) = u;
      }
    }
  }
}

// ---- fused flash attention, swapped-QK^T in-register softmax ----
// QBLK=128, 8 waves x 16 q-rows. K/V DOUBLE-buffered with issue-early staging:
// one __syncthreads per KV-tile drains only the loads issued a full
// compute-phase earlier -> HBM latency hides under QK^T/softmax/PV.
// XCD-grouping swizzle: all 8 qb-blocks of a head on one XCD (K/V L2 reuse).
__global__ __launch_bounds__(512) void k_attn(
    const unsigned short* __restrict__ QKn, const unsigned short* __restrict__ Vt,
    unsigned short* __restrict__ O) {
  __shared__ __align__(16) unsigned short Ks[2][64 * 64];   // [kpos][d], swizzled
  __shared__ __align__(16) unsigned short Vs[2][64 * 64];   // [d][kpos], swizzled
  __shared__ __align__(16) unsigned short Ps[8][16 * 72];   // per-wave P [q][kpos]
  const int tid = threadIdx.x;
  const int lane = tid & 63, w = tid >> 6;
  const int ln15 = lane & 15, lh = lane >> 4;
  // XCD-grouping: 1536 blocks, 192 per XCD-chunk; qb fastest within a head
  const int o = blockIdx.x;
  const int sid = (o & 7) * 192 + (o >> 3);
  const int qb = sid & 7;
  const int bhid = sid >> 3;
  const int h = bhid % NHEAD;
  const int b = bhid / NHEAD;
  const size_t bh = (size_t)(b * NHEAD + h);
  const unsigned short* Qbase = QKn + (size_t)(b * SEQ + qb * 128 + w * 16) * NQK + h * HDIM;
  const unsigned short* Kbase = QKn + (size_t)(b * SEQ) * NQK + DMODEL + h * HDIM;
  const unsigned short* Vbase = Vt + bh * HDIM * SEQ;

  const int srow = lane >> 3;
  const int sblk = ((lane & 7) ^ srow) * 8;
  const int swz = (ln15 & 7) << 3;

  auto stage = [&](int kb, int s) {
    const int row = w * 8 + srow;
    gload_lds16(Kbase + (size_t)(kb * 64 + row) * NQK + sblk, &Ks[s][w * 512]);
    gload_lds16(Vbase + (size_t)row * SEQ + kb * 64 + sblk, &Vs[s][w * 512]);
  };

  bf16x8 aq[2];
#pragma unroll
  for (int ch = 0; ch < 2; ++ch)
    aq[ch] = *reinterpret_cast<const bf16x8*>(Qbase + (size_t)ln15 * NQK + ch * 32 + lh * 8);

  f32x4 acc[4] = {};
  float mr = -1e30f, lr = 0.f;

  stage(0, 0);
  for (int kb = 0; kb < SEQ / 64; ++kb) {
    const int s = kb & 1;
    __syncthreads();                            // drains stage(kb); frees buf s^1
    if (kb + 1 < SEQ / 64) stage(kb + 1, s ^ 1);  // issue-early: overlaps compute

    f32x4 sv[4] = {};
    __builtin_amdgcn_s_setprio(1);
#pragma unroll
    for (int t = 0; t < 4; ++t) {
#pragma unroll
      for (int ch = 0; ch < 2; ++ch) {
        bf16x8 bk = *reinterpret_cast<const bf16x8*>(
            &Ks[s][(t * 16 + ln15) * 64 + ((ch * 32 + lh * 8) ^ swz)]);
        sv[t] = __builtin_amdgcn_mfma_f32_16x16x32_bf16(bk, aq[ch], sv[t], 0, 0, 0);
      }
    }
    __builtin_amdgcn_s_setprio(0);

    float bm;
    {
      const float a0 = fmaxf(fmaxf(sv[0][0], sv[0][1]), fmaxf(sv[0][2], sv[0][3]));
      const float a1 = fmaxf(fmaxf(sv[1][0], sv[1][1]), fmaxf(sv[1][2], sv[1][3]));
      const float a2 = fmaxf(fmaxf(sv[2][0], sv[2][1]), fmaxf(sv[2][2], sv[2][3]));
      const float a3 = fmaxf(fmaxf(sv[3][0], sv[3][1]), fmaxf(sv[3][2], sv[3][3]));
      bm = fmaxf(fmaxf(a0, a1), fmaxf(a2, a3));
    }
    bm = fmaxf(bm, __shfl_xor(bm, 16));
    bm = fmaxf(bm, __shfl_xor(bm, 32));
    const int grow = __any(bm > mr + 8.f);
    float al = 1.f;
    if (grow) {
      const float mn = fmaxf(mr, bm);
      al = __builtin_amdgcn_exp2f(mr - mn);
      mr = mn;
    }
#pragma unroll
    for (int t = 0; t < 4; ++t)
#pragma unroll
      for (int r = 0; r < 4; ++r) sv[t][r] = __builtin_amdgcn_exp2f(sv[t][r] - mr);
    float rs;
    {
      const float a0 = (sv[0][0] + sv[0][1]) + (sv[0][2] + sv[0][3]);
      const float a1 = (sv[1][0] + sv[1][1]) + (sv[1][2] + sv[1][3]);
      const float a2 = (sv[2][0] + sv[2][1]) + (sv[2][2] + sv[2][3]);
      const float a3 = (sv[3][0] + sv[3][1]) + (sv[3][2] + sv[3][3]);
      rs = (a0 + a1) + (a2 + a3);
    }
    rs += __shfl_xor(rs, 16);
    rs += __shfl_xor(rs, 32);
    lr = lr * al + rs;
    if (grow) {
      float alq[4];
#pragma unroll
      for (int r = 0; r < 4; ++r) alq[r] = __shfl(al, lh * 4 + r);
#pragma unroll
      for (int dt = 0; dt < 4; ++dt)
#pragma unroll
        for (int r = 0; r < 4; ++r) acc[dt][r] *= alq[r];
    }

#pragma unroll
    for (int t = 0; t < 4; ++t) {
      uint2 u;
      u.x = cvt_pk_bf16(sv[t][0], sv[t][1]);
      u.y = cvt_pk_bf16(sv[t][2], sv[t][3]);
      *reinterpret_cast<uint2*>(&Ps[w][ln15 * 72 + t * 16 + lh * 4]) = u;
    }

    bf16x8 ap[2];
#pragma unroll
    for (int ch = 0; ch < 2; ++ch)
      ap[ch] = *reinterpret_cast<const bf16x8*>(&Ps[w][ln15 * 72 + ch * 32 + lh * 8]);
    __builtin_amdgcn_s_setprio(1);
#pragma unroll
    for (int dt = 0; dt < 4; ++dt) {
#pragma unroll
      for (int ch = 0; ch < 2; ++ch) {
        bf16x8 bv = *reinterpret_cast<const bf16x8*>(
            &Vs[s][(dt * 16 + ln15) * 64 + ((ch * 32 + lh * 8) ^ swz)]);
        acc[dt] = __builtin_amdgcn_mfma_f32_16x16x32_bf16(ap[ch], bv, acc[dt], 0, 0, 0);
      }
    }
    __builtin_amdgcn_s_setprio(0);
  }

  float lrq[4];
#pragma unroll
  for (int r = 0; r < 4; ++r) lrq[r] = 1.0f / __shfl(lr, lh * 4 + r);
  const int qrow = qb * 128 + w * 16 + lh * 4;
#pragma unroll
  for (int dt = 0; dt < 4; ++dt)
#pragma unroll
    for (int r = 0; r < 4; ++r)
      O[((size_t)b * SEQ + qrow + r) * DMODEL + h * 64 + dt * 16 + ln15] = f2bf(acc[dt][r] * lrq[r]);
}

extern "C" void kernel_launch(void* const* d_in, const int* in_sizes, int n_in,
                              void* d_out, int out_size, void* d_ws, size_t ws_size,
                              hipStream_t stream) {
  const float* x      = (const float*)d_in[0];
  const float* qkv_w  = (const float*)d_in[1];
  const float* proj_w = (const float*)d_in[2];
  const float* proj_b = (const float*)d_in[3];
  float* out = (float*)d_out;

  char* ws = (char*)d_ws;
  const size_t SZ_XB   = (size_t)MTOT * DMODEL * 2;   // x bf16; reused as attn-out bf16
  const size_t SZ_WQT  = (size_t)NQKV * DMODEL * 2;
  const size_t SZ_WPT  = (size_t)DMODEL * DMODEL * 2;
  const size_t SZ_QK   = (size_t)MTOT * NQK * 2;      // natural Q|K [m][1536]
  const size_t SZ_VT   = (size_t)BB * NHEAD * HDIM * SEQ * 2;
  unsigned short* Xb   = (unsigned short*)ws;
  unsigned short* WqT  = (unsigned short*)(ws + SZ_XB);
  unsigned short* WpT  = (unsigned short*)(ws + SZ_XB + SZ_WQT);
  unsigned short* QKn  = (unsigned short*)(ws + SZ_XB + SZ_WQT + SZ_WPT);
  unsigned short* Vt   = (unsigned short*)(ws + SZ_XB + SZ_WQT + SZ_WPT + SZ_QK);
  if (ws_size < SZ_XB + SZ_WQT + SZ_WPT + SZ_QK + SZ_VT) return;

  // 1) x -> bf16
  k_cvt_bf16<<<2048, 256, 0, stream>>>((const float4*)x, (ushort4*)Xb, MTOT * DMODEL / 4);
  // 2) weight transposes (f32 -> bf16, B^T layout); Q-columns pre-scaled by QSCALE
  k_transpose_bf16<<<dim3(NQKV / 32, DMODEL / 32), 256, 0, stream>>>(qkv_w, WqT, DMODEL, NQKV, DMODEL);
  k_transpose_bf16<<<dim3(DMODEL / 32, DMODEL / 32), 256, 0, stream>>>(proj_w, WpT, DMODEL, DMODEL, 0);
  // 3) QKV projection -> natural Q|K [m][1536] + packed V^T. 128^2 tiles, m-fastest.
  k_gemm_bt<1><<<dim3(MTOT / 128, NQKV / 128), 256, 0, stream>>>(
      Xb, WqT, MTOT, NQKV, DMODEL, nullptr, nullptr, QKn, Vt);
  // 4) fused attention -> Oattn (reuses Xb region; Xb is dead after step 3)
  k_attn<<<BB * NHEAD * 8, 512, 0, stream>>>(QKn, Vt, Xb);
  // 5) output projection + bias -> f32 out
  k_gemm_bt<0><<<dim3(MTOT / 128, DMODEL / 128), 256, 0, stream>>>(
      Xb, WpT, MTOT, DMODEL, DMODEL, out, proj_b, nullptr, nullptr);
}

// Round 11
// 173.966 us; speedup vs baseline: 2.1633x; 1.0699x over previous
//
#include <hip/hip_runtime.h>
#include <cstdint>
#include <cstddef>

typedef float f32x4 __attribute__((ext_vector_type(4)));
typedef __bf16 bf16x8 __attribute__((ext_vector_type(8)));

#define BB 16
#define SEQ 1024
#define DMODEL 768
#define NHEAD 12
#define HDIM 64
#define MTOT (BB * SEQ)
#define NQKV (3 * DMODEL)
#define NQK (2 * DMODEL)   // natural-layout Q|K row length
// 0.125 (hd^-0.5) * log2(e): QK^T then exp2 == exp(0.125 * qk)
#define QSCALE 0.18033688011112042f

static __device__ __forceinline__ unsigned short f2bf(float f) {
  unsigned int u = __builtin_bit_cast(unsigned int, f);
  u += 0x7fffu + ((u >> 16) & 1u);
  return (unsigned short)(u >> 16);
}

static __device__ __forceinline__ unsigned cvt_pk_bf16(float lo, float hi) {
  unsigned r;
  asm("v_cvt_pk_bf16_f32 %0, %1, %2" : "=v"(r) : "v"(lo), "v"(hi));
  return r;
}

static __device__ __forceinline__ void gload_lds16(const void* g, void* l) {
  __builtin_amdgcn_global_load_lds((__attribute__((address_space(1))) void*)g,
                                   (__attribute__((address_space(3))) void*)l,
                                   16, 0, 0);
}

// ---- prep: f32 -> bf16 convert (vectorized) ----
__global__ void k_cvt_bf16(const float4* __restrict__ in, ushort4* __restrict__ out, int n4) {
  int stride = gridDim.x * blockDim.x;
  for (int i = blockIdx.x * blockDim.x + threadIdx.x; i < n4; i += stride) {
    float4 v = in[i];
    ushort4 o;
    o.x = f2bf(v.x); o.y = f2bf(v.y); o.z = f2bf(v.z); o.w = f2bf(v.w);
    out[i] = o;
  }
}

// ---- prep: transpose f32 [R][C] -> bf16 [C][R]; cols < scaleN get *QSCALE ----
__global__ void k_transpose_bf16(const float* __restrict__ in, unsigned short* __restrict__ out,
                                 int R, int C, int scaleN) {
  __shared__ float tile[32][33];
  int tx = threadIdx.x & 31, ty = threadIdx.x >> 5;
  int c0 = blockIdx.x * 32, r0 = blockIdx.y * 32;
#pragma unroll
  for (int i = 0; i < 4; ++i)
    tile[ty + i * 8][tx] = in[(size_t)(r0 + ty + i * 8) * C + c0 + tx];
  __syncthreads();
#pragma unroll
  for (int i = 0; i < 4; ++i) {
    const int n = c0 + ty + i * 8;  // original column = output row
    float v = tile[tx][ty + i * 8];
    if (n < scaleN) v *= QSCALE;
    out[(size_t)n * R + r0 + tx] = f2bf(v);
  }
}

// ---- GEMM C[M,N] = A[M,K] * Bt[N,K]^T, bf16 in, f32 accum ----
// m97 geometry: 128x128 tile, BK=64 single-buffered (32 KB LDS), 2 barriers per
// K-step, 4 waves each computing 64x64 (acc 4x4 = 64 AGPR), 3 blocks/CU.
// T2 swizzle both-sides (rule 21).
// MODE 0: outF = C + bias. MODE 1: natural Q|K [m][1536] + packed V^T.
template <int MODE>
__global__ __launch_bounds__(256, 3) void k_gemm_bt(
    const unsigned short* __restrict__ A, const unsigned short* __restrict__ Bt,
    int M, int N, int K,
    float* __restrict__ outF, const float* __restrict__ bias,
    unsigned short* __restrict__ QK, unsigned short* __restrict__ Vt) {
  __shared__ __align__(16) unsigned short As[128 * 64];  // 16 KB
  __shared__ __align__(16) unsigned short Bs[128 * 64];  // 16 KB
  const int tid = threadIdx.x;
  const int lane = tid & 63, wid = tid >> 6;
  const int ln15 = lane & 15, lh = lane >> 4;
  const int wr = wid >> 1, wc = wid & 1;
  const int m0 = blockIdx.x * 128, n0 = blockIdx.y * 128;
  f32x4 acc[4][4] = {};
  const int srow = lane >> 3;
  const int sblk = ((lane & 7) ^ srow) * 8;
  const int swz = (ln15 & 7) << 3;
  const int nk = K >> 6;

  for (int kt = 0; kt < nk; ++kt) {
    const int k0 = kt * 64;
#pragma unroll
    for (int c = 0; c < 4; ++c) {
      const int ch = wid * 4 + c;
      const int row = ch * 8 + srow;
      gload_lds16(A + (size_t)(m0 + row) * K + k0 + sblk, &As[ch * 512]);
      gload_lds16(Bt + (size_t)(n0 + row) * K + k0 + sblk, &Bs[ch * 512]);
    }
    __syncthreads();
#pragma unroll
    for (int kk = 0; kk < 2; ++kk) {
      const int kc = kk * 32 + lh * 8;
      bf16x8 af[4], bfv[4];
#pragma unroll
      for (int mt = 0; mt < 4; ++mt)
        af[mt] = *reinterpret_cast<const bf16x8*>(
            &As[(wr * 64 + mt * 16 + ln15) * 64 + (kc ^ swz)]);
#pragma unroll
      for (int nn = 0; nn < 4; ++nn)
        bfv[nn] = *reinterpret_cast<const bf16x8*>(
            &Bs[(wc * 64 + nn * 16 + ln15) * 64 + (kc ^ swz)]);
#pragma unroll
      for (int mt = 0; mt < 4; ++mt)
#pragma unroll
        for (int nn = 0; nn < 4; ++nn)
          acc[mt][nn] = __builtin_amdgcn_mfma_f32_16x16x32_bf16(af[mt], bfv[nn], acc[mt][nn], 0, 0, 0);
    }
    __syncthreads();
  }

#pragma unroll
  for (int mt = 0; mt < 4; ++mt) {
#pragma unroll
    for (int nn = 0; nn < 4; ++nn) {
      const int nb = n0 + wc * 64 + nn * 16;
      const int mb = m0 + wr * 64 + mt * 16 + lh * 4;
      if (MODE == 0) {
#pragma unroll
        for (int r = 0; r < 4; ++r)
          outF[(size_t)(mb + r) * N + nb + ln15] = acc[mt][nn][r] + bias[nb + ln15];
      } else if (nb < NQK) {
#pragma unroll
        for (int r = 0; r < 4; ++r)
          QK[(size_t)(mb + r) * NQK + nb + ln15] = f2bf(acc[mt][nn][r]);
      } else {
        const int rr = nb + ln15 - NQK;
        const int h = rr >> 6, d = rr & 63;
        const int b = mb >> 10, nr0 = mb & 1023;
        ushort4 u;
        u.x = f2bf(acc[mt][nn][0]); u.y = f2bf(acc[mt][nn][1]);
        u.z = f2bf(acc[mt][nn][2]); u.w = f2bf(acc[mt][nn][3]);
        *reinterpret_cast<ushort4*>(
            &Vt[(((size_t)b * NHEAD + h) * HDIM + d) * SEQ + nr0]) = u;
      }
    }
  }
}

// ---- fused flash attention, swapped-QK^T, low-VALU softmax ----
// QBLK=128, 8 waves. K/V double-buffered, issue-early staging, XCD-grouping.
// Softmax restructure (this round):
//  * C-fold: sv initialized to -mr -> MFMA output IS (qk - mr); no sub pass.
//  * ones-MFMA row-sum: accl = mfma(P, 1s, accl); PV layout puts q=lh*4+r in
//    elem r -> final 1/accl[r] needs no shuffle. Replaces 15-add tree+3 shfl.
//  * grow check on in-lane partial max via __any (no shuffles steady-state);
//    full-row max + delta-subtract + rescale only inside the rare grow branch.
//  * mr starts at 0 (not -1e30) so the C-fold is exact; P bounded by 2^8.
__global__ __launch_bounds__(512) void k_attn(
    const unsigned short* __restrict__ QKn, const unsigned short* __restrict__ Vt,
    unsigned short* __restrict__ O) {
  __shared__ __align__(16) unsigned short Ks[2][64 * 64];   // [kpos][d], swizzled
  __shared__ __align__(16) unsigned short Vs[2][64 * 64];   // [d][kpos], swizzled
  __shared__ __align__(16) unsigned short Ps[8][16 * 72];   // per-wave P [q][kpos]
  const int tid = threadIdx.x;
  const int lane = tid & 63, w = tid >> 6;
  const int ln15 = lane & 15, lh = lane >> 4;
  const int o = blockIdx.x;
  const int sid = (o & 7) * 192 + (o >> 3);
  const int qb = sid & 7;
  const int bhid = sid >> 3;
  const int h = bhid % NHEAD;
  const int b = bhid / NHEAD;
  const size_t bh = (size_t)(b * NHEAD + h);
  const unsigned short* Qbase = QKn + (size_t)(b * SEQ + qb * 128 + w * 16) * NQK + h * HDIM;
  const unsigned short* Kbase = QKn + (size_t)(b * SEQ) * NQK + DMODEL + h * HDIM;
  const unsigned short* Vbase = Vt + bh * HDIM * SEQ;

  const int srow = lane >> 3;
  const int sblk = ((lane & 7) ^ srow) * 8;
  const int swz = (ln15 & 7) << 3;

  auto stage = [&](int kb, int s) {
    const int row = w * 8 + srow;
    gload_lds16(Kbase + (size_t)(kb * 64 + row) * NQK + sblk, &Ks[s][w * 512]);
    gload_lds16(Vbase + (size_t)row * SEQ + kb * 64 + sblk, &Vs[s][w * 512]);
  };

  bf16x8 aq[2];
#pragma unroll
  for (int ch = 0; ch < 2; ++ch)
    aq[ch] = *reinterpret_cast<const bf16x8*>(Qbase + (size_t)ln15 * NQK + ch * 32 + lh * 8);

  bf16x8 onesb;
#pragma unroll
  for (int i = 0; i < 8; ++i) onesb[i] = (__bf16)1.0f;

  f32x4 acc[4] = {};
  f32x4 accl = {};          // row-sums via ones-MFMA; elem r <-> q-row lh*4+r
  float mr = 0.f;           // running max (log2 domain)
  f32x4 cinit = {};         // splat(-mr)

  stage(0, 0);
  for (int kb = 0; kb < SEQ / 64; ++kb) {
    const int s = kb & 1;
    __syncthreads();
    if (kb + 1 < SEQ / 64) stage(kb + 1, s ^ 1);

    // S^T = K Q^T with C = -mr  ->  sv holds (qk - mr)
    f32x4 sv[4];
#pragma unroll
    for (int t = 0; t < 4; ++t) sv[t] = cinit;
    __builtin_amdgcn_s_setprio(1);
#pragma unroll
    for (int t = 0; t < 4; ++t) {
#pragma unroll
      for (int ch = 0; ch < 2; ++ch) {
        bf16x8 bk = *reinterpret_cast<const bf16x8*>(
            &Ks[s][(t * 16 + ln15) * 64 + ((ch * 32 + lh * 8) ^ swz)]);
        sv[t] = __builtin_amdgcn_mfma_f32_16x16x32_bf16(bk, aq[ch], sv[t], 0, 0, 0);
      }
    }
    __builtin_amdgcn_s_setprio(0);

    // in-lane partial max (max3-friendly nesting)
    float pm;
    {
      const float a0 = fmaxf(fmaxf(sv[0][0], sv[0][1]), fmaxf(sv[0][2], sv[0][3]));
      const float a1 = fmaxf(fmaxf(sv[1][0], sv[1][1]), fmaxf(sv[1][2], sv[1][3]));
      const float a2 = fmaxf(fmaxf(sv[2][0], sv[2][1]), fmaxf(sv[2][2], sv[2][3]));
      const float a3 = fmaxf(fmaxf(sv[3][0], sv[3][1]), fmaxf(sv[3][2], sv[3][3]));
      pm = fmaxf(fmaxf(a0, a1), fmaxf(a2, a3));
    }
    // defer-max: rescale only when some row grew past +8 (P bounded by 2^8)
    if (__any(pm > 8.f)) {
      float bmf = pm;
      bmf = fmaxf(bmf, __shfl_xor(bmf, 16));
      bmf = fmaxf(bmf, __shfl_xor(bmf, 32));          // full-row (qk - mr) max
      const float delta = fmaxf(bmf, 0.f);            // per-row max growth
      const float al = __builtin_amdgcn_exp2f(-delta);
#pragma unroll
      for (int t = 0; t < 4; ++t)
#pragma unroll
        for (int r = 0; r < 4; ++r) sv[t][r] -= delta;
      mr += delta;
      cinit[0] = -mr; cinit[1] = -mr; cinit[2] = -mr; cinit[3] = -mr;
      float alq[4];
#pragma unroll
      for (int r = 0; r < 4; ++r) alq[r] = __shfl(al, lh * 4 + r);
#pragma unroll
      for (int dt = 0; dt < 4; ++dt)
#pragma unroll
        for (int r = 0; r < 4; ++r) acc[dt][r] *= alq[r];
#pragma unroll
      for (int r = 0; r < 4; ++r) accl[r] *= alq[r];
    }

#pragma unroll
    for (int t = 0; t < 4; ++t)
#pragma unroll
      for (int r = 0; r < 4; ++r) sv[t][r] = __builtin_amdgcn_exp2f(sv[t][r]);

    // pack P -> LDS (A-fragment redistribution)
#pragma unroll
    for (int t = 0; t < 4; ++t) {
      uint2 u;
      u.x = cvt_pk_bf16(sv[t][0], sv[t][1]);
      u.y = cvt_pk_bf16(sv[t][2], sv[t][3]);
      *reinterpret_cast<uint2*>(&Ps[w][ln15 * 72 + t * 16 + lh * 4]) = u;
    }

    bf16x8 ap[2];
#pragma unroll
    for (int ch = 0; ch < 2; ++ch)
      ap[ch] = *reinterpret_cast<const bf16x8*>(&Ps[w][ln15 * 72 + ch * 32 + lh * 8]);
    __builtin_amdgcn_s_setprio(1);
#pragma unroll
    for (int ch = 0; ch < 2; ++ch)   // row-sum MFMA (replaces add-tree + shuffles)
      accl = __builtin_amdgcn_mfma_f32_16x16x32_bf16(ap[ch], onesb, accl, 0, 0, 0);
#pragma unroll
    for (int dt = 0; dt < 4; ++dt) {
#pragma unroll
      for (int ch = 0; ch < 2; ++ch) {
        bf16x8 bv = *reinterpret_cast<const bf16x8*>(
            &Vs[s][(dt * 16 + ln15) * 64 + ((ch * 32 + lh * 8) ^ swz)]);
        acc[dt] = __builtin_amdgcn_mfma_f32_16x16x32_bf16(ap[ch], bv, acc[dt], 0, 0, 0);
      }
    }
    __builtin_amdgcn_s_setprio(0);
  }

  const int qrow = qb * 128 + w * 16 + lh * 4;
#pragma unroll
  for (int dt = 0; dt < 4; ++dt)
#pragma unroll
    for (int r = 0; r < 4; ++r)
      O[((size_t)b * SEQ + qrow + r) * DMODEL + h * 64 + dt * 16 + ln15] =
          f2bf(acc[dt][r] / accl[r]);
}

extern "C" void kernel_launch(void* const* d_in, const int* in_sizes, int n_in,
                              void* d_out, int out_size, void* d_ws, size_t ws_size,
                              hipStream_t stream) {
  const float* x      = (const float*)d_in[0];
  const float* qkv_w  = (const float*)d_in[1];
  const float* proj_w = (const float*)d_in[2];
  const float* proj_b = (const float*)d_in[3];
  float* out = (float*)d_out;

  char* ws = (char*)d_ws;
  const size_t SZ_XB   = (size_t)MTOT * DMODEL * 2;   // x bf16; reused as attn-out bf16
  const size_t SZ_WQT  = (size_t)NQKV * DMODEL * 2;
  const size_t SZ_WPT  = (size_t)DMODEL * DMODEL * 2;
  const size_t SZ_QK   = (size_t)MTOT * NQK * 2;      // natural Q|K [m][1536]
  const size_t SZ_VT   = (size_t)BB * NHEAD * HDIM * SEQ * 2;
  unsigned short* Xb   = (unsigned short*)ws;
  unsigned short* WqT  = (unsigned short*)(ws + SZ_XB);
  unsigned short* WpT  = (unsigned short*)(ws + SZ_XB + SZ_WQT);
  unsigned short* QKn  = (unsigned short*)(ws + SZ_XB + SZ_WQT + SZ_WPT);
  unsigned short* Vt   = (unsigned short*)(ws + SZ_XB + SZ_WQT + SZ_WPT + SZ_QK);
  if (ws_size < SZ_XB + SZ_WQT + SZ_WPT + SZ_QK + SZ_VT) return;

  // 1) x -> bf16
  k_cvt_bf16<<<2048, 256, 0, stream>>>((const float4*)x, (ushort4*)Xb, MTOT * DMODEL / 4);
  // 2) weight transposes (f32 -> bf16, B^T layout); Q-columns pre-scaled by QSCALE
  k_transpose_bf16<<<dim3(NQKV / 32, DMODEL / 32), 256, 0, stream>>>(qkv_w, WqT, DMODEL, NQKV, DMODEL);
  k_transpose_bf16<<<dim3(DMODEL / 32, DMODEL / 32), 256, 0, stream>>>(proj_w, WpT, DMODEL, DMODEL, 0);
  // 3) QKV projection -> natural Q|K [m][1536] + packed V^T. 128^2 tiles, m-fastest.
  k_gemm_bt<1><<<dim3(MTOT / 128, NQKV / 128), 256, 0, stream>>>(
      Xb, WqT, MTOT, NQKV, DMODEL, nullptr, nullptr, QKn, Vt);
  // 4) fused attention -> Oattn (reuses Xb region; Xb is dead after step 3)
  k_attn<<<BB * NHEAD * 8, 512, 0, stream>>>(QKn, Vt, Xb);
  // 5) output projection + bias -> f32 out
  k_gemm_bt<0><<<dim3(MTOT / 128, DMODEL / 128), 256, 0, stream>>>(
      Xb, WpT, MTOT, DMODEL, DMODEL, out, proj_b, nullptr, nullptr);
}

// Round 12
// 168.517 us; speedup vs baseline: 2.2332x; 1.0323x over previous
//
#include <hip/hip_runtime.h>
#include <cstdint>
#include <cstddef>

typedef float f32x4 __attribute__((ext_vector_type(4)));
typedef __bf16 bf16x8 __attribute__((ext_vector_type(8)));

#define BB 16
#define SEQ 1024
#define DMODEL 768
#define NHEAD 12
#define HDIM 64
#define MTOT (BB * SEQ)
#define NQKV (3 * DMODEL)
#define NQK (2 * DMODEL)   // natural-layout Q|K row length
// 0.125 (hd^-0.5) * log2(e): QK^T then exp2 == exp(0.125 * qk)
#define QSCALE 0.18033688011112042f

static __device__ __forceinline__ unsigned short f2bf(float f) {
  unsigned int u = __builtin_bit_cast(unsigned int, f);
  u += 0x7fffu + ((u >> 16) & 1u);
  return (unsigned short)(u >> 16);
}

static __device__ __forceinline__ unsigned cvt_pk_bf16(float lo, float hi) {
  unsigned r;
  asm("v_cvt_pk_bf16_f32 %0, %1, %2" : "=v"(r) : "v"(lo), "v"(hi));
  return r;
}

static __device__ __forceinline__ float max3f(float a, float b, float c) {
  return fmaxf(fmaxf(a, b), c);   // clang fuses to v_max3_f32 (T17)
}

static __device__ __forceinline__ void gload_lds16(const void* g, void* l) {
  __builtin_amdgcn_global_load_lds((__attribute__((address_space(1))) void*)g,
                                   (__attribute__((address_space(3))) void*)l,
                                   16, 0, 0);
}

// ---- fused prep: x->bf16 cvt (blocks 0..1023) + both weight transposes ----
// transpose blocks: qkv_w grid 72x24 (blocks 1024..2751), proj_w 24x24 (2752..3327).
__global__ __launch_bounds__(256) void k_prep(
    const float4* __restrict__ x4, ushort4* __restrict__ xb4,
    const float* __restrict__ qkv_w, unsigned short* __restrict__ WqT,
    const float* __restrict__ proj_w, unsigned short* __restrict__ WpT) {
  const int blk = blockIdx.x;
  if (blk < 1024) {
    const int n4 = MTOT * DMODEL / 4;
    const int stride = 1024 * 256;
    for (int i = blk * 256 + threadIdx.x; i < n4; i += stride) {
      float4 v = x4[i];
      ushort4 o;
      o.x = f2bf(v.x); o.y = f2bf(v.y); o.z = f2bf(v.z); o.w = f2bf(v.w);
      xb4[i] = o;
    }
    return;
  }
  __shared__ float tile[32][33];
  const float* in; unsigned short* out; int C, scaleN, bx, by;
  if (blk < 1024 + 1728) {
    const int l = blk - 1024; bx = l % 72; by = l / 72;
    in = qkv_w; out = WqT; C = NQKV; scaleN = DMODEL;
  } else {
    const int l = blk - 2752; bx = l % 24; by = l / 24;
    in = proj_w; out = WpT; C = DMODEL; scaleN = 0;
  }
  const int R = DMODEL;
  const int tx = threadIdx.x & 31, ty = threadIdx.x >> 5;
  const int c0 = bx * 32, r0 = by * 32;
#pragma unroll
  for (int i = 0; i < 4; ++i)
    tile[ty + i * 8][tx] = in[(size_t)(r0 + ty + i * 8) * C + c0 + tx];
  __syncthreads();
#pragma unroll
  for (int i = 0; i < 4; ++i) {
    const int n = c0 + ty + i * 8;  // original column = output row
    float v = tile[tx][ty + i * 8];
    if (n < scaleN) v *= QSCALE;
    out[(size_t)n * R + r0 + tx] = f2bf(v);
  }
}

// ---- GEMM C[M,N] = A[M,K] * Bt[N,K]^T, bf16 in, f32 accum ----
// m97 geometry: 128x128 tile, BK=64 single-buffered (32 KB LDS), 2 barriers per
// K-step, 4 waves each computing 64x64 (acc 4x4 = 64 AGPR), now 4 blocks/CU
// (launch_bounds(256,4): 128 KB LDS, ~124 regs/wave fits the 16-wave budget).
// T2 swizzle both-sides (rule 21).
// MODE 0: outF = C + bias. MODE 1: natural Q|K [m][1536] + packed V^T.
template <int MODE>
__global__ __launch_bounds__(256, 4) void k_gemm_bt(
    const unsigned short* __restrict__ A, const unsigned short* __restrict__ Bt,
    int M, int N, int K,
    float* __restrict__ outF, const float* __restrict__ bias,
    unsigned short* __restrict__ QK, unsigned short* __restrict__ Vt) {
  __shared__ __align__(16) unsigned short As[128 * 64];  // 16 KB
  __shared__ __align__(16) unsigned short Bs[128 * 64];  // 16 KB
  const int tid = threadIdx.x;
  const int lane = tid & 63, wid = tid >> 6;
  const int ln15 = lane & 15, lh = lane >> 4;
  const int wr = wid >> 1, wc = wid & 1;
  const int m0 = blockIdx.x * 128, n0 = blockIdx.y * 128;
  f32x4 acc[4][4] = {};
  const int srow = lane >> 3;
  const int sblk = ((lane & 7) ^ srow) * 8;
  const int swz = (ln15 & 7) << 3;
  const int nk = K >> 6;

  for (int kt = 0; kt < nk; ++kt) {
    const int k0 = kt * 64;
#pragma unroll
    for (int c = 0; c < 4; ++c) {
      const int ch = wid * 4 + c;
      const int row = ch * 8 + srow;
      gload_lds16(A + (size_t)(m0 + row) * K + k0 + sblk, &As[ch * 512]);
      gload_lds16(Bt + (size_t)(n0 + row) * K + k0 + sblk, &Bs[ch * 512]);
    }
    __syncthreads();
#pragma unroll
    for (int kk = 0; kk < 2; ++kk) {
      const int kc = kk * 32 + lh * 8;
      bf16x8 af[4], bfv[4];
#pragma unroll
      for (int mt = 0; mt < 4; ++mt)
        af[mt] = *reinterpret_cast<const bf16x8*>(
            &As[(wr * 64 + mt * 16 + ln15) * 64 + (kc ^ swz)]);
#pragma unroll
      for (int nn = 0; nn < 4; ++nn)
        bfv[nn] = *reinterpret_cast<const bf16x8*>(
            &Bs[(wc * 64 + nn * 16 + ln15) * 64 + (kc ^ swz)]);
#pragma unroll
      for (int mt = 0; mt < 4; ++mt)
#pragma unroll
        for (int nn = 0; nn < 4; ++nn)
          acc[mt][nn] = __builtin_amdgcn_mfma_f32_16x16x32_bf16(af[mt], bfv[nn], acc[mt][nn], 0, 0, 0);
    }
    __syncthreads();
  }

#pragma unroll
  for (int mt = 0; mt < 4; ++mt) {
#pragma unroll
    for (int nn = 0; nn < 4; ++nn) {
      const int nb = n0 + wc * 64 + nn * 16;
      const int mb = m0 + wr * 64 + mt * 16 + lh * 4;
      if (MODE == 0) {
#pragma unroll
        for (int r = 0; r < 4; ++r)
          outF[(size_t)(mb + r) * N + nb + ln15] = acc[mt][nn][r] + bias[nb + ln15];
      } else if (nb < NQK) {
#pragma unroll
        for (int r = 0; r < 4; ++r)
          QK[(size_t)(mb + r) * NQK + nb + ln15] = f2bf(acc[mt][nn][r]);
      } else {
        const int rr = nb + ln15 - NQK;
        const int h = rr >> 6, d = rr & 63;
        const int b = mb >> 10, nr0 = mb & 1023;
        ushort4 u;
        u.x = f2bf(acc[mt][nn][0]); u.y = f2bf(acc[mt][nn][1]);
        u.z = f2bf(acc[mt][nn][2]); u.w = f2bf(acc[mt][nn][3]);
        *reinterpret_cast<ushort4*>(
            &Vt[(((size_t)b * NHEAD + h) * HDIM + d) * SEQ + nr0]) = u;
      }
    }
  }
}

// ---- fused flash attention, swapped-QK^T, low-VALU softmax ----
// QBLK=128, 8 waves. K/V double-buffered, issue-early staging, XCD-grouping.
// C-fold (-mr in MFMA C), ones-MFMA row-sum, defer-max with __any gate,
// max3-balanced partial-max tree (7 ops, depth 3).
__global__ __launch_bounds__(512) void k_attn(
    const unsigned short* __restrict__ QKn, const unsigned short* __restrict__ Vt,
    unsigned short* __restrict__ O) {
  __shared__ __align__(16) unsigned short Ks[2][64 * 64];   // [kpos][d], swizzled
  __shared__ __align__(16) unsigned short Vs[2][64 * 64];   // [d][kpos], swizzled
  __shared__ __align__(16) unsigned short Ps[8][16 * 72];   // per-wave P [q][kpos]
  const int tid = threadIdx.x;
  const int lane = tid & 63, w = tid >> 6;
  const int ln15 = lane & 15, lh = lane >> 4;
  const int o = blockIdx.x;
  const int sid = (o & 7) * 192 + (o >> 3);
  const int qb = sid & 7;
  const int bhid = sid >> 3;
  const int h = bhid % NHEAD;
  const int b = bhid / NHEAD;
  const size_t bh = (size_t)(b * NHEAD + h);
  const unsigned short* Qbase = QKn + (size_t)(b * SEQ + qb * 128 + w * 16) * NQK + h * HDIM;
  const unsigned short* Kbase = QKn + (size_t)(b * SEQ) * NQK + DMODEL + h * HDIM;
  const unsigned short* Vbase = Vt + bh * HDIM * SEQ;

  const int srow = lane >> 3;
  const int sblk = ((lane & 7) ^ srow) * 8;
  const int swz = (ln15 & 7) << 3;

  auto stage = [&](int kb, int s) {
    const int row = w * 8 + srow;
    gload_lds16(Kbase + (size_t)(kb * 64 + row) * NQK + sblk, &Ks[s][w * 512]);
    gload_lds16(Vbase + (size_t)row * SEQ + kb * 64 + sblk, &Vs[s][w * 512]);
  };

  bf16x8 aq[2];
#pragma unroll
  for (int ch = 0; ch < 2; ++ch)
    aq[ch] = *reinterpret_cast<const bf16x8*>(Qbase + (size_t)ln15 * NQK + ch * 32 + lh * 8);

  bf16x8 onesb;
#pragma unroll
  for (int i = 0; i < 8; ++i) onesb[i] = (__bf16)1.0f;

  f32x4 acc[4] = {};
  f32x4 accl = {};          // row-sums via ones-MFMA; elem r <-> q-row lh*4+r
  float mr = 0.f;           // running max (log2 domain)
  f32x4 cinit = {};         // splat(-mr)

  stage(0, 0);
  for (int kb = 0; kb < SEQ / 64; ++kb) {
    const int s = kb & 1;
    __syncthreads();
    if (kb + 1 < SEQ / 64) stage(kb + 1, s ^ 1);

    // S^T = K Q^T with C = -mr  ->  sv holds (qk - mr)
    f32x4 sv[4];
#pragma unroll
    for (int t = 0; t < 4; ++t) sv[t] = cinit;
    __builtin_amdgcn_s_setprio(1);
#pragma unroll
    for (int t = 0; t < 4; ++t) {
#pragma unroll
      for (int ch = 0; ch < 2; ++ch) {
        bf16x8 bk = *reinterpret_cast<const bf16x8*>(
            &Ks[s][(t * 16 + ln15) * 64 + ((ch * 32 + lh * 8) ^ swz)]);
        sv[t] = __builtin_amdgcn_mfma_f32_16x16x32_bf16(bk, aq[ch], sv[t], 0, 0, 0);
      }
    }
    __builtin_amdgcn_s_setprio(0);

    // in-lane partial max: balanced max3 tree (7 ops, depth 3)
    float pm;
    {
      const float g0 = max3f(sv[0][0], sv[0][1], sv[0][2]);
      const float g1 = max3f(sv[0][3], sv[1][0], sv[1][1]);
      const float g2 = max3f(sv[1][2], sv[1][3], sv[2][0]);
      const float g3 = max3f(sv[2][1], sv[2][2], sv[2][3]);
      const float g4 = max3f(sv[3][0], sv[3][1], sv[3][2]);
      pm = fmaxf(max3f(g0, g1, g2), max3f(g3, g4, sv[3][3]));
    }
    // defer-max: rescale only when some row grew past +8 (P bounded by 2^8)
    if (__any(pm > 8.f)) {
      float bmf = pm;
      bmf = fmaxf(bmf, __shfl_xor(bmf, 16));
      bmf = fmaxf(bmf, __shfl_xor(bmf, 32));          // full-row (qk - mr) max
      const float delta = fmaxf(bmf, 0.f);
      const float al = __builtin_amdgcn_exp2f(-delta);
#pragma unroll
      for (int t = 0; t < 4; ++t)
#pragma unroll
        for (int r = 0; r < 4; ++r) sv[t][r] -= delta;
      mr += delta;
      cinit[0] = -mr; cinit[1] = -mr; cinit[2] = -mr; cinit[3] = -mr;
      float alq[4];
#pragma unroll
      for (int r = 0; r < 4; ++r) alq[r] = __shfl(al, lh * 4 + r);
#pragma unroll
      for (int dt = 0; dt < 4; ++dt)
#pragma unroll
        for (int r = 0; r < 4; ++r) acc[dt][r] *= alq[r];
#pragma unroll
      for (int r = 0; r < 4; ++r) accl[r] *= alq[r];
    }

#pragma unroll
    for (int t = 0; t < 4; ++t)
#pragma unroll
      for (int r = 0; r < 4; ++r) sv[t][r] = __builtin_amdgcn_exp2f(sv[t][r]);

    // pack P -> LDS (A-fragment redistribution)
#pragma unroll
    for (int t = 0; t < 4; ++t) {
      uint2 u;
      u.x = cvt_pk_bf16(sv[t][0], sv[t][1]);
      u.y = cvt_pk_bf16(sv[t][2], sv[t][3]);
      *reinterpret_cast<uint2*>(&Ps[w][ln15 * 72 + t * 16 + lh * 4]) = u;
    }

    bf16x8 ap[2];
#pragma unroll
    for (int ch = 0; ch < 2; ++ch)
      ap[ch] = *reinterpret_cast<const bf16x8*>(&Ps[w][ln15 * 72 + ch * 32 + lh * 8]);
    __builtin_amdgcn_s_setprio(1);
#pragma unroll
    for (int ch = 0; ch < 2; ++ch)   // row-sum MFMA
      accl = __builtin_amdgcn_mfma_f32_16x16x32_bf16(ap[ch], onesb, accl, 0, 0, 0);
#pragma unroll
    for (int dt = 0; dt < 4; ++dt) {
#pragma unroll
      for (int ch = 0; ch < 2; ++ch) {
        bf16x8 bv = *reinterpret_cast<const bf16x8*>(
            &Vs[s][(dt * 16 + ln15) * 64 + ((ch * 32 + lh * 8) ^ swz)]);
        acc[dt] = __builtin_amdgcn_mfma_f32_16x16x32_bf16(ap[ch], bv, acc[dt], 0, 0, 0);
      }
    }
    __builtin_amdgcn_s_setprio(0);
  }

  const int qrow = qb * 128 + w * 16 + lh * 4;
#pragma unroll
  for (int dt = 0; dt < 4; ++dt)
#pragma unroll
    for (int r = 0; r < 4; ++r)
      O[((size_t)b * SEQ + qrow + r) * DMODEL + h * 64 + dt * 16 + ln15] =
          f2bf(acc[dt][r] / accl[r]);
}

extern "C" void kernel_launch(void* const* d_in, const int* in_sizes, int n_in,
                              void* d_out, int out_size, void* d_ws, size_t ws_size,
                              hipStream_t stream) {
  const float* x      = (const float*)d_in[0];
  const float* qkv_w  = (const float*)d_in[1];
  const float* proj_w = (const float*)d_in[2];
  const float* proj_b = (const float*)d_in[3];
  float* out = (float*)d_out;

  char* ws = (char*)d_ws;
  const size_t SZ_XB   = (size_t)MTOT * DMODEL * 2;   // x bf16; reused as attn-out bf16
  const size_t SZ_WQT  = (size_t)NQKV * DMODEL * 2;
  const size_t SZ_WPT  = (size_t)DMODEL * DMODEL * 2;
  const size_t SZ_QK   = (size_t)MTOT * NQK * 2;      // natural Q|K [m][1536]
  const size_t SZ_VT   = (size_t)BB * NHEAD * HDIM * SEQ * 2;
  unsigned short* Xb   = (unsigned short*)ws;
  unsigned short* WqT  = (unsigned short*)(ws + SZ_XB);
  unsigned short* WpT  = (unsigned short*)(ws + SZ_XB + SZ_WQT);
  unsigned short* QKn  = (unsigned short*)(ws + SZ_XB + SZ_WQT + SZ_WPT);
  unsigned short* Vt   = (unsigned short*)(ws + SZ_XB + SZ_WQT + SZ_WPT + SZ_QK);
  if (ws_size < SZ_XB + SZ_WQT + SZ_WPT + SZ_QK + SZ_VT) return;

  // 1) fused prep: x->bf16 + both weight transposes (Q-cols pre-scaled by QSCALE)
  k_prep<<<3328, 256, 0, stream>>>((const float4*)x, (ushort4*)Xb,
                                   qkv_w, WqT, proj_w, WpT);
  // 2) QKV projection -> natural Q|K [m][1536] + packed V^T. 128^2 tiles, m-fastest.
  k_gemm_bt<1><<<dim3(MTOT / 128, NQKV / 128), 256, 0, stream>>>(
      Xb, WqT, MTOT, NQKV, DMODEL, nullptr, nullptr, QKn, Vt);
  // 3) fused attention -> Oattn (reuses Xb region; Xb is dead after step 2)
  k_attn<<<BB * NHEAD * 8, 512, 0, stream>>>(QKn, Vt, Xb);
  // 4) output projection + bias -> f32 out
  k_gemm_bt<0><<<dim3(MTOT / 128, DMODEL / 128), 256, 0, stream>>>(
      Xb, WpT, MTOT, DMODEL, DMODEL, out, proj_b, nullptr, nullptr);
}